// Round 10
// baseline (210.240 us; speedup 1.0000x reference)
//
#include <hip/hip_runtime.h>
#include <hip/hip_bf16.h>
#include <math.h>

// Problem constants
#define D_MODEL 256
#define DEPTH 2
#define D_INNER 512
#define D_STATE 16
#define D_CONV 4
#define DT_RANK 16
#define BATCH 2
#define SEQLEN 2048
#define MROWS (BATCH * SEQLEN)   // 4096

#define LCH 8     // rows per chunk
#define NCH 512   // total chunks
#define CPB 256   // chunks per batch
#define BAR_FLAGS 64

typedef __attribute__((ext_vector_type(8))) short bf16x8;
typedef __attribute__((ext_vector_type(4))) float f32x4;

__device__ __forceinline__ float silu(float v) {
    return v / (1.0f + __expf(-v));
}

__device__ __forceinline__ ushort f2bf(float f) {
    union { float f; unsigned u; } v; v.f = f;
    unsigned r = v.u + 0x7FFFu + ((v.u >> 16) & 1u);
    return (ushort)(r >> 16);
}

__device__ __forceinline__ float bf2f(ushort u) {
    union { unsigned u; float f; } v; v.u = ((unsigned)u) << 16;
    return v.f;
}

__device__ __forceinline__ float softplus_f(float x) {
    return (x > 20.f) ? x : __logf(1.f + __expf(x));
}

// Coherence-point accessors for cross-block data (Ssum/sdsum): relaxed
// agent-scope atomics lower to write-through / cache-bypassing accesses —
// correct across non-coherent XCD L2s with NO buffer_wbl2 / buffer_inv.
__device__ __forceinline__ void cp_store(float* p, float v) {
    __hip_atomic_store(p, v, __ATOMIC_RELAXED, __HIP_MEMORY_SCOPE_AGENT);
}
__device__ __forceinline__ float cp_load(const float* p) {
    return __hip_atomic_load(p, __ATOMIC_RELAXED, __HIP_MEMORY_SCOPE_AGENT);
}

// Grid-wide barrier with ZERO cache maintenance (fix for R4/R5 regressions).
// Correctness: hipcc drains vmcnt(0) at the __syncthreads before arrival, so
// every wave's write-through Ssum stores are at the coherence point before
// any lane increments the counter. Readers use coherence-point loads, so no
// invalidate is needed. Spin on 64 spread flags (128B apart) via relaxed RMW.
__device__ __forceinline__ void gridbar(unsigned* bar, unsigned k) {
    __syncthreads();   // compiler emits s_waitcnt vmcnt(0) before s_barrier
    if (threadIdx.x == 0) {
        asm volatile("s_waitcnt vmcnt(0)" ::: "memory");  // belt & braces
        unsigned old = __hip_atomic_fetch_add(&bar[0], 1u, __ATOMIC_RELAXED,
                                              __HIP_MEMORY_SCOPE_AGENT);
        if (old == k * NCH - 1u) {
            #pragma unroll
            for (int i = 0; i < BAR_FLAGS; i++)
                __hip_atomic_fetch_add(&bar[32 + i * 32], 1u, __ATOMIC_RELAXED,
                                       __HIP_MEMORY_SCOPE_AGENT);
        } else {
            unsigned* f = &bar[32 + (blockIdx.x & (BAR_FLAGS - 1)) * 32];
            while (__hip_atomic_fetch_add(f, 0u, __ATOMIC_RELAXED,
                                          __HIP_MEMORY_SCOPE_AGENT) < k)
                __builtin_amdgcn_s_sleep(8);
        }
    }
    __syncthreads();
}

#define XS_STR 260   // f32 stride, 11-row LN tile
#define HS_STR 264   // ushort stride, bf16 LN output
#define XC_STR 520   // ushort stride, xc/yy LDS tiles

// ---------------------------------------------------------------------------
// k_cvt: f32 -> bf16 tile-major weights + zero barrier state.
// ---------------------------------------------------------------------------
__global__ __launch_bounds__(256) void k_cvt(
    const float* __restrict__ ipw, const float* __restrict__ xpw,
    const float* __restrict__ opw, ushort* __restrict__ ipwT,
    ushort* __restrict__ xpwT, ushort* __restrict__ opwT,
    unsigned* __restrict__ bar)
{
    size_t tid = (size_t)blockIdx.x * 256 + threadIdx.x;
    if (tid < 32 + BAR_FLAGS * 32) bar[tid] = 0u;
    {   // ipw: [2][1024 n][256 k] -> per layer [64 nt][8 kt][16 r][32 c]
        int lyr = (int)(tid >> 16), rem = (int)(tid & 65535);
        int n = rem >> 6, k = (rem & 63) * 4;
        float4 v = *(const float4*)(ipw + ((size_t)lyr * 1024 + n) * 256 + k);
        int nt = n >> 4, r = n & 15, kt = k >> 5, c = k & 31;
        ushort4 o = { f2bf(v.x), f2bf(v.y), f2bf(v.z), f2bf(v.w) };
        *(ushort4*)(ipwT + (size_t)lyr * 262144 + (nt * 8 + kt) * 512 + r * 32 + c) = o;
    }
    if (tid < 12288) {   // xpw
        int lyr = (int)(tid / 6144), rem = (int)(tid % 6144);
        int n = rem >> 7, k = (rem & 127) * 4;
        float4 v = *(const float4*)(xpw + ((size_t)lyr * 48 + n) * 512 + k);
        int nt = n >> 4, r = n & 15, kt = k >> 5, c = k & 31;
        ushort4 o = { f2bf(v.x), f2bf(v.y), f2bf(v.z), f2bf(v.w) };
        *(ushort4*)(xpwT + (size_t)lyr * 24576 + (nt * 16 + kt) * 512 + r * 32 + c) = o;
    }
    if (tid < 65536) {   // opw
        int lyr = (int)(tid >> 15), rem = (int)(tid & 32767);
        int n = rem >> 7, k = (rem & 127) * 4;
        float4 v = *(const float4*)(opw + ((size_t)lyr * 256 + n) * 512 + k);
        int nt = n >> 4, r = n & 15, kt = k >> 5, c = k & 31;
        ushort4 o = { f2bf(v.x), f2bf(v.y), f2bf(v.z), f2bf(v.w) };
        *(ushort4*)(opwT + (size_t)lyr * 131072 + (nt * 16 + kt) * 512 + r * 32 + c) = o;
    }
}

// ---------------------------------------------------------------------------
// k_fused: one dispatch per layer. Grid 512 x 512, fully co-resident
// (bounds(512,4): VGPR<=128 -> 2 blocks/CU; LDS 56.7KB -> 2/CU).
//   Phase A (R9 front): stage | LN | in_proj+in-reg conv | x_proj | scan.
//     xc/z/dbl stay in LDS; Ssum/sdsum via coherence-point stores.
//   gridbar -> Phase B (comb): two-level prefix, coherence-point accesses.
//   gridbar -> Phase C (back): rescan from true h_init (params in regs),
//     gate, out_proj + residual.
// ---------------------------------------------------------------------------
__global__ __launch_bounds__(512, 4) void k_fused(
    const float* __restrict__ xin, const float* __restrict__ lnwL,
    const float* __restrict__ lnbL, const ushort* __restrict__ ipwT,
    const float* __restrict__ cwL, const float* __restrict__ cbL,
    const ushort* __restrict__ xpwT, const float* __restrict__ dpwL,
    const float* __restrict__ dpbL, const float* __restrict__ alogL,
    const float* __restrict__ dparL, const ushort* __restrict__ opwT,
    float* __restrict__ Ssum, float* __restrict__ sdsum,
    unsigned* __restrict__ bar, unsigned epoch0,
    float* __restrict__ xout)
{
    const int t = threadIdx.x, bid = blockIdx.x;
    const int lane = t & 63, w = t >> 6, l15 = lane & 15, quad = lane >> 4;

    __shared__ __align__(16) char smem[56704];
    // transient pool [0, 30144): phase-dependent overlays
    float*  xs    = (float*)(smem);            // 11440 B (dead after LN)
    ushort* hs    = (ushort*)(smem + 11456);   //  8448 B (dead after in_proj)
    float4* cw_s  = (float4*)(smem + 19904);   //  8192 B (dead after in_proj)
    float*  cb_s  = (float*)(smem + 28096);    //  2048 B (dead after in_proj)
    float*  S_l   = (float*)(smem);            //  2176 B (phase B)
    float*  sd_l  = (float*)(smem + 2176);     //  2176 B (phase B)
    ushort* yy_s  = (ushort*)(smem);           // 16640 B (phase C)
    // persistent pool [30208, 56704): live phase A -> C
    ushort* xc_s  = (ushort*)(smem + 30208);   // 16640 B
    ushort* z_s   = (ushort*)(smem + 46848);   //  8192 B
    float*  dbl_s = (float*)(smem + 55040);    //  1664 B

    int m0 = bid * LCH;

    // ================= Phase A =================
    // ---- stage x rows m0-3 .. m0+7 (clamp row<0) + conv weights ----
    cw_s[t] = *(const float4*)(cwL + t * 4);
    cb_s[t] = cbL[t];
    for (int i = t; i < 11 * 64; i += 512) {
        int r = i >> 6, c = (i & 63) * 4;
        int grow = m0 - 3 + r; if (grow < 0) grow = 0;
        float4 v = *(const float4*)(xin + (size_t)grow * D_MODEL + c);
        *(float4*)&xs[r * XS_STR + c] = v;
    }
    __syncthreads();

    // ---- LayerNorm, 11 rows x 32 threads ----
    if (t < 11 * 32) {
        int r = t >> 5, ci = t & 31;
        float s = 0.f, sq = 0.f;
        #pragma unroll
        for (int k = 0; k < 8; k++) {
            float v = xs[r * XS_STR + ci + 32 * k];
            s += v; sq += v * v;
        }
        #pragma unroll
        for (int off = 1; off < 32; off <<= 1) {
            s  += __shfl_xor(s, off, 32);
            sq += __shfl_xor(sq, off, 32);
        }
        float mu  = s * (1.0f / 256.f);
        float var = sq * (1.0f / 256.f) - mu * mu;
        float rst = rsqrtf(var + 1e-5f);
        #pragma unroll
        for (int k = 0; k < 8; k++) {
            int c = ci + 32 * k;
            float v = (xs[r * XS_STR + c] - mu) * rst * lnwL[c] + lnbL[c];
            hs[r * HS_STR + c] = f2bf(v);
        }
    }
    __syncthreads();

    // ---- in_proj MFMA (f split 4+4, 2-deep weight dbuf) + fused conv ----
    {
        bf16x8 af[8];
        #pragma unroll
        for (int k8 = 0; k8 < 8; k8++)
            af[k8] = *(const bf16x8*)&hs[l15 * HS_STR + quad * 8 + k8 * 32];
        const ushort* wb = ipwT + (size_t)w * 64 * 512 + l15 * 32 + quad * 8;

        #pragma unroll
        for (int half = 0; half < 2; half++) {
            const ushort* wh = wb + (size_t)half * 4 * 8 * 512;
            f32x4 acc[4];
            #pragma unroll
            for (int f = 0; f < 4; f++) acc[f] = (f32x4){0.f, 0.f, 0.f, 0.f};
            bf16x8 bA[4], bB[4];
            #pragma unroll
            for (int f = 0; f < 4; f++) bA[f] = *(const bf16x8*)(wh + (f * 8) * 512);
            #pragma unroll
            for (int k8 = 0; k8 < 8; k8++) {
                bf16x8* cur = (k8 & 1) ? bB : bA;
                bf16x8* nxt = (k8 & 1) ? bA : bB;
                if (k8 < 7) {
                    #pragma unroll
                    for (int f = 0; f < 4; f++)
                        nxt[f] = *(const bf16x8*)(wh + (f * 8 + k8 + 1) * 512);
                }
                #pragma unroll
                for (int f = 0; f < 4; f++)
                    acc[f] = __builtin_amdgcn_mfma_f32_16x16x32_bf16(af[k8], cur[f], acc[f], 0, 0, 0);
            }

            if (w < 4) {
                // fused conv (R9-verified): xi rows live in acc across quads.
                #pragma unroll
                for (int f = 0; f < 4; f++) {
                    int n = w * 128 + (half * 4 + f) * 16 + l15;
                    float x0 = acc[f][0], x1 = acc[f][1], x2 = acc[f][2], x3 = acc[f][3];
                    float p1 = __shfl_up(x1, 16);
                    float p2 = __shfl_up(x2, 16);
                    float p3 = __shfl_up(x3, 16);
                    float4 cwv = cw_s[n];
                    float cbv = cb_s[n];
                    int jb = quad * 4 - 3;
                    #define EMIT(JOFF, T0, T1, T2, T3)                          \
                    {   int j = jb + (JOFF);                                    \
                        if (j >= 0 && j < 8) {                                  \
                            int l = (m0 + j) & (SEQLEN - 1);                    \
                            float s = cbv;                                      \
                            if (l >= 3) s = fmaf(cwv.x, (T0), s);               \
                            if (l >= 2) s = fmaf(cwv.y, (T1), s);               \
                            if (l >= 1) s = fmaf(cwv.z, (T2), s);               \
                            s = fmaf(cwv.w, (T3), s);                           \
                            xc_s[j * XC_STR + n] = f2bf(silu(s));               \
                        }                                                       \
                    }
                    EMIT(0, p1, p2, p3, x0)
                    EMIT(1, p2, p3, x0, x1)
                    EMIT(2, p3, x0, x1, x2)
                    EMIT(3, x0, x1, x2, x3)
                    #undef EMIT
                }
            } else {
                // z path: n >= 512, valid rows rl 3..10 -> local rows 0..7
                #pragma unroll
                for (int f = 0; f < 4; f++) {
                    int n = w * 128 + (half * 4 + f) * 16 + l15;
                    #pragma unroll
                    for (int r2 = 0; r2 < 4; r2++) {
                        int rl = quad * 4 + r2;
                        if (rl >= 3 && rl < 11)
                            z_s[(rl - 3) * 512 + (n - 512)] = f2bf(silu(acc[f][r2]));
                    }
                }
            }
        }
    }

    // ---- hoist scan params + compute a[] (overlaps x_proj phase) ----
    float a[16], wdp[16];
    {
        float al[16];
        *(float4*)&al[0]   = *(const float4*)(alogL + (size_t)t * 16 + 0);
        *(float4*)&al[4]   = *(const float4*)(alogL + (size_t)t * 16 + 4);
        *(float4*)&al[8]   = *(const float4*)(alogL + (size_t)t * 16 + 8);
        *(float4*)&al[12]  = *(const float4*)(alogL + (size_t)t * 16 + 12);
        #pragma unroll
        for (int n = 0; n < 16; n++) a[n] = -__expf(al[n]);
    }
    *(float4*)&wdp[0]  = *(const float4*)(dpwL + (size_t)t * 16 + 0);
    *(float4*)&wdp[4]  = *(const float4*)(dpwL + (size_t)t * 16 + 4);
    *(float4*)&wdp[8]  = *(const float4*)(dpwL + (size_t)t * 16 + 8);
    *(float4*)&wdp[12] = *(const float4*)(dpwL + (size_t)t * 16 + 12);
    float bias = dpbL[t];
    float Dd = dparL[t];
    __syncthreads();

    // ---- x_proj MFMA (waves 0..2) -> dbl_s (LDS only) ----
    if (w < 3) {
        const ushort* wb = xpwT + (size_t)w * 16 * 512 + l15 * 32 + quad * 8;
        bf16x8 bw[16];
        #pragma unroll
        for (int k8 = 0; k8 < 16; k8++)
            bw[k8] = *(const bf16x8*)(wb + k8 * 512);
        f32x4 acc = (f32x4){0.f, 0.f, 0.f, 0.f};
        #pragma unroll
        for (int k8 = 0; k8 < 16; k8++) {
            bf16x8 af = *(const bf16x8*)&xc_s[l15 * XC_STR + quad * 8 + k8 * 32];
            acc = __builtin_amdgcn_mfma_f32_16x16x32_bf16(af, bw[k8], acc, 0, 0, 0);
        }
        int n = w * 16 + l15;
        #pragma unroll
        for (int r2 = 0; r2 < 4; r2++) {
            int rl = quad * 4 + r2;
            if (rl < LCH) dbl_s[rl * 52 + n] = acc[r2];
        }
    }
    __syncthreads();

    // ---- local scan summary (d = t), 8 serial steps -> Ssum/sdsum (CP) ----
    {
        float h[16];
        #pragma unroll
        for (int n = 0; n < 16; n++) h[n] = 0.f;
        float sd = 0.f;
        for (int j = 0; j < LCH; j++) {
            const float* dp = &dbl_s[j * 52];
            float d0 = 0.f, d1 = 0.f;
            #pragma unroll
            for (int r2 = 0; r2 < 8; r2++) {
                d0 = fmaf(dp[r2], wdp[r2], d0);
                d1 = fmaf(dp[8 + r2], wdp[8 + r2], d1);
            }
            float dl = softplus_f(bias + d0 + d1);
            float xv = bf2f(xc_s[j * XC_STR + t]);
            float u = dl * xv;
            sd += dl;
            #pragma unroll
            for (int n = 0; n < 16; n++)
                h[n] = fmaf(__expf(dl * a[n]), h[n], dp[16 + n] * u);
        }
        size_t sbase = (size_t)bid * 16 * D_INNER + t;
        #pragma unroll
        for (int n = 0; n < 16; n++)
            cp_store(&Ssum[sbase + (size_t)n * D_INNER], h[n]);
        cp_store(&sdsum[(size_t)bid * D_INNER + t], sd);
    }

    // ================= barrier 1 =================
    gridbar(bar, epoch0 + 1);

    // ================= Phase B (comb) =================
    {
        int ch32 = t & 31, seg = t >> 5;
        int chain = bid * 32 + ch32;
        int d = chain & 511;
        int n = (chain >> 9) & 15;
        int b = chain >> 13;
        float ac = -__expf(alogL[(size_t)d * 16 + n]);
        int c0 = b * CPB + seg * 16;

        float s_r[16], sd_r[16];
        float S = 0.f, sdt = 0.f;
        #pragma unroll
        for (int j = 0; j < 16; j++) {
            size_t c = (size_t)(c0 + j);
            float s  = cp_load(&Ssum[(c * 16 + n) * D_INNER + d]);
            float sv = cp_load(&sdsum[c * D_INNER + d]);
            s_r[j] = s; sd_r[j] = sv;
            S = fmaf(__expf(ac * sv), S, s);
            sdt += sv;
        }
        S_l[ch32 * 17 + seg] = S;
        sd_l[ch32 * 17 + seg] = sdt;
        __syncthreads();

        if (t < 32) {
            float hi = 0.f;
            #pragma unroll
            for (int g = 0; g < 16; g++) {
                float Sv = S_l[t * 17 + g], sdv = sd_l[t * 17 + g];
                S_l[t * 17 + g] = hi;
                hi = fmaf(__expf(ac * sdv), hi, Sv);
            }
        }
        __syncthreads();

        float hi = S_l[ch32 * 17 + seg];
        #pragma unroll
        for (int j = 0; j < 16; j++) {
            size_t c = (size_t)(c0 + j);
            cp_store(&Ssum[(c * 16 + n) * D_INNER + d], hi);
            hi = fmaf(__expf(ac * sd_r[j]), hi, s_r[j]);
        }
    }

    // ================= barrier 2 =================
    gridbar(bar, epoch0 + 2);

    // ================= Phase C (back) =================
    {
        float h[16];
        size_t sbase = (size_t)bid * 16 * D_INNER + t;
        #pragma unroll
        for (int n = 0; n < 16; n++)
            h[n] = cp_load(&Ssum[sbase + (size_t)n * D_INNER]);
        for (int j = 0; j < LCH; j++) {
            const float* dp = &dbl_s[j * 52];
            float d0 = 0.f, d1 = 0.f;
            #pragma unroll
            for (int r2 = 0; r2 < 8; r2++) {
                d0 = fmaf(dp[r2], wdp[r2], d0);
                d1 = fmaf(dp[8 + r2], wdp[8 + r2], d1);
            }
            float dl = softplus_f(bias + d0 + d1);
            float xv = bf2f(xc_s[j * XC_STR + t]);
            float gate = bf2f(z_s[j * 512 + t]);
            float u = dl * xv;
            float y0 = 0.f, y1 = 0.f, y2 = 0.f, y3 = 0.f;
            #pragma unroll
            for (int q = 0; q < 4; q++) {
                h[4 * q + 0] = fmaf(__expf(dl * a[4 * q + 0]), h[4 * q + 0], dp[16 + 4 * q + 0] * u);
                h[4 * q + 1] = fmaf(__expf(dl * a[4 * q + 1]), h[4 * q + 1], dp[16 + 4 * q + 1] * u);
                h[4 * q + 2] = fmaf(__expf(dl * a[4 * q + 2]), h[4 * q + 2], dp[16 + 4 * q + 2] * u);
                h[4 * q + 3] = fmaf(__expf(dl * a[4 * q + 3]), h[4 * q + 3], dp[16 + 4 * q + 3] * u);
                y0 = fmaf(h[4 * q + 0], dp[32 + 4 * q + 0], y0);
                y1 = fmaf(h[4 * q + 1], dp[32 + 4 * q + 1], y1);
                y2 = fmaf(h[4 * q + 2], dp[32 + 4 * q + 2], y2);
                y3 = fmaf(h[4 * q + 3], dp[32 + 4 * q + 3], y3);
            }
            float y = (y0 + y1) + (y2 + y3) + xv * Dd;
            yy_s[j * XC_STR + t] = f2bf(y * gate);
        }
    }
    __syncthreads();

    // ---- out_proj MFMA + residual (8 rows valid, per-k8 LDS af) ----
    {
        const ushort* wb = opwT + (size_t)w * 2 * 16 * 512 + l15 * 32 + quad * 8;
        f32x4 acc0 = (f32x4){0.f, 0.f, 0.f, 0.f};
        f32x4 acc1 = (f32x4){0.f, 0.f, 0.f, 0.f};
        bf16x8 bA0 = *(const bf16x8*)(wb + 0 * 512);
        bf16x8 bA1 = *(const bf16x8*)(wb + 16 * 512);
        bf16x8 bB0, bB1;
        #pragma unroll
        for (int k8 = 0; k8 < 16; k8++) {
            if (k8 < 15) {
                if (k8 & 1) { bA0 = *(const bf16x8*)(wb + (k8 + 1) * 512);
                              bA1 = *(const bf16x8*)(wb + (16 + k8 + 1) * 512); }
                else        { bB0 = *(const bf16x8*)(wb + (k8 + 1) * 512);
                              bB1 = *(const bf16x8*)(wb + (16 + k8 + 1) * 512); }
            }
            bf16x8 af = *(const bf16x8*)&yy_s[l15 * XC_STR + quad * 8 + k8 * 32];
            bf16x8 c0 = (k8 & 1) ? bB0 : bA0;
            bf16x8 c1 = (k8 & 1) ? bB1 : bA1;
            acc0 = __builtin_amdgcn_mfma_f32_16x16x32_bf16(af, c0, acc0, 0, 0, 0);
            acc1 = __builtin_amdgcn_mfma_f32_16x16x32_bf16(af, c1, acc1, 0, 0, 0);
        }
        #pragma unroll
        for (int f = 0; f < 2; f++) {
            int n = w * 32 + f * 16 + l15;
            const f32x4& acc = (f == 0) ? acc0 : acc1;
            #pragma unroll
            for (int r2 = 0; r2 < 4; r2++) {
                int rl = quad * 4 + r2;
                if (rl < LCH) {
                    int row = m0 + rl;
                    xout[(size_t)row * D_MODEL + n] =
                        acc[r2] + xin[(size_t)row * D_MODEL + n];
                }
            }
        }
    }
}

// ---------------------------------------------------------------------------
// Launch. Inter-layer activation routed through d_out.
// ---------------------------------------------------------------------------
extern "C" void kernel_launch(void* const* d_in, const int* in_sizes, int n_in,
                              void* d_out, int out_size, void* d_ws, size_t ws_size,
                              hipStream_t stream)
{
    const float* x    = (const float*)d_in[0];
    const float* lnw  = (const float*)d_in[1];
    const float* lnb  = (const float*)d_in[2];
    const float* ipw  = (const float*)d_in[3];
    const float* cw   = (const float*)d_in[4];
    const float* cb   = (const float*)d_in[5];
    const float* xpw  = (const float*)d_in[6];
    const float* dpw  = (const float*)d_in[7];
    const float* dpb  = (const float*)d_in[8];
    const float* alog = (const float*)d_in[9];
    const float* dpar = (const float*)d_in[10];
    const float* opw  = (const float*)d_in[11];
    float* out = (float*)d_out;

    char* p = (char*)d_ws;
    auto alloc = [&](size_t bytes) { char* r = p; p += (bytes + 255) & ~(size_t)255; return r; };
    float*  Ssum  = (float*)alloc((size_t)NCH * 16 * D_INNER * 4);
    float*  sdsum = (float*)alloc((size_t)NCH * D_INNER * 4);
    ushort* ipwT  = (ushort*)alloc((size_t)DEPTH * 262144 * 2);
    ushort* xpwT  = (ushort*)alloc((size_t)DEPTH * 24576 * 2);
    ushort* opwT  = (ushort*)alloc((size_t)DEPTH * 131072 * 2);
    unsigned* bar = (unsigned*)alloc((32 + BAR_FLAGS * 32) * 4);

    k_cvt<<<512, 256, 0, stream>>>(ipw, xpw, opw, ipwT, xpwT, opwT, bar);

    for (int lyr = 0; lyr < DEPTH; lyr++) {
        const float* xin = (lyr == 0) ? x : out;
        float* xout = out;

        k_fused<<<NCH, 512, 0, stream>>>(
            xin, lnw + lyr * D_MODEL, lnb + lyr * D_MODEL,
            ipwT + (size_t)lyr * 262144,
            cw + (size_t)lyr * D_INNER * D_CONV, cb + lyr * D_INNER,
            xpwT + (size_t)lyr * 24576,
            dpw + (size_t)lyr * D_INNER * DT_RANK, dpb + lyr * D_INNER,
            alog + (size_t)lyr * D_INNER * D_STATE, dpar + lyr * D_INNER,
            opwT + (size_t)lyr * 131072,
            Ssum, sdsum, bar, (unsigned)(lyr * 2), out);
    }
}

// Round 11
// 203.140 us; speedup vs baseline: 1.0350x; 1.0350x over previous
//
#include <hip/hip_runtime.h>
#include <hip/hip_bf16.h>
#include <math.h>

// Problem constants
#define D_MODEL 256
#define DEPTH 2
#define D_INNER 512
#define D_STATE 16
#define D_CONV 4
#define DT_RANK 16
#define BATCH 2
#define SEQLEN 2048
#define MROWS (BATCH * SEQLEN)   // 4096

#define LCH 8     // rows per chunk (front)
#define NCH 512   // total chunks
#define CPB 256   // chunks per batch

typedef __attribute__((ext_vector_type(8))) short bf16x8;
typedef __attribute__((ext_vector_type(4))) float f32x4;

__device__ __forceinline__ float silu(float v) {
    return v / (1.0f + __expf(-v));
}

__device__ __forceinline__ ushort f2bf(float f) {
    union { float f; unsigned u; } v; v.f = f;
    unsigned r = v.u + 0x7FFFu + ((v.u >> 16) & 1u);
    return (ushort)(r >> 16);
}

__device__ __forceinline__ float bf2f(ushort u) {
    union { unsigned u; float f; } v; v.u = ((unsigned)u) << 16;
    return v.f;
}

__device__ __forceinline__ float softplus_f(float x) {
    return (x > 20.f) ? x : __logf(1.f + __expf(x));
}

#define XS_STR 260   // f32 stride, 11-row LN tile
#define HS_STR 264   // ushort stride, bf16 LN output (16 rows, 11 valid)
#define XC_STR 520   // ushort stride, xc/yy LDS tiles

// ---------------------------------------------------------------------------
// k_cvt: f32 -> bf16 AND re-layout to MFMA tile-major: per (nt,kt) a 1-KB
// tile [16 r][32 c] so one wave weight-load = one coalesced 1-KB segment.
// ---------------------------------------------------------------------------
__global__ __launch_bounds__(256) void k_cvt(
    const float* __restrict__ ipw, const float* __restrict__ xpw,
    const float* __restrict__ opw, ushort* __restrict__ ipwT,
    ushort* __restrict__ xpwT, ushort* __restrict__ opwT)
{
    size_t tid = (size_t)blockIdx.x * 256 + threadIdx.x;
    {   // ipw: [2][1024 n][256 k] -> per layer [64 nt][8 kt][16 r][32 c]
        int lyr = (int)(tid >> 16), rem = (int)(tid & 65535);
        int n = rem >> 6, k = (rem & 63) * 4;
        float4 v = *(const float4*)(ipw + ((size_t)lyr * 1024 + n) * 256 + k);
        int nt = n >> 4, r = n & 15, kt = k >> 5, c = k & 31;
        ushort4 o = { f2bf(v.x), f2bf(v.y), f2bf(v.z), f2bf(v.w) };
        *(ushort4*)(ipwT + (size_t)lyr * 262144 + (nt * 8 + kt) * 512 + r * 32 + c) = o;
    }
    if (tid < 12288) {   // xpw: [2][48][512] -> per layer [3 nt][16 kt] tiles
        int lyr = (int)(tid / 6144), rem = (int)(tid % 6144);
        int n = rem >> 7, k = (rem & 127) * 4;
        float4 v = *(const float4*)(xpw + ((size_t)lyr * 48 + n) * 512 + k);
        int nt = n >> 4, r = n & 15, kt = k >> 5, c = k & 31;
        ushort4 o = { f2bf(v.x), f2bf(v.y), f2bf(v.z), f2bf(v.w) };
        *(ushort4*)(xpwT + (size_t)lyr * 24576 + (nt * 16 + kt) * 512 + r * 32 + c) = o;
    }
    if (tid < 65536) {   // opw: [2][256][512] -> per layer [16 nt][16 kt]
        int lyr = (int)(tid >> 15), rem = (int)(tid & 32767);
        int n = rem >> 7, k = (rem & 127) * 4;
        float4 v = *(const float4*)(opw + ((size_t)lyr * 256 + n) * 512 + k);
        int nt = n >> 4, r = n & 15, kt = k >> 5, c = k & 31;
        ushort4 o = { f2bf(v.x), f2bf(v.y), f2bf(v.z), f2bf(v.w) };
        *(ushort4*)(opwT + (size_t)lyr * 131072 + (nt * 16 + kt) * 512 + r * 32 + c) = o;
    }
}

// ---------------------------------------------------------------------------
// k_front: 8-row chunk, 5 phases / 4 barriers.
//   stage (x + conv weights) | LN | in_proj MFMA + in-register conv (xi never
//   touches LDS; xc -> LDS only, z -> LDS only) | x_proj MFMA on waves 0-2
//   WHILE waves 3-7 stream xc_s/z_s to global as coalesced ushort4 | scan.
// Grid 512 x 512, 2 blocks/CU.
// ---------------------------------------------------------------------------
__global__ __launch_bounds__(512, 4) void k_front(
    const float* __restrict__ xin, const float* __restrict__ lnwL,
    const float* __restrict__ lnbL, const ushort* __restrict__ ipwT,
    const float* __restrict__ cwL, const float* __restrict__ cbL,
    const ushort* __restrict__ xpwT, const float* __restrict__ dpwL,
    const float* __restrict__ dpbL, const float* __restrict__ alogL,
    ushort* __restrict__ zsB, ushort* __restrict__ xcB,
    float* __restrict__ dbl, float* __restrict__ Ssum,
    float* __restrict__ sdsum)
{
    const int t = threadIdx.x, bid = blockIdx.x;
    const int lane = t & 63, w = t >> 6, l15 = lane & 15, quad = lane >> 4;
    __shared__ float  xs[11 * XS_STR];                     // 11.4 KB
    __shared__ ushort hs[16 * HS_STR];                     //  8.4 KB
    __shared__ __align__(16) ushort xc_s[16 * XC_STR];     // 16.6 KB
    __shared__ __align__(16) ushort z_s[8 * 512];          //  8.2 KB
    __shared__ float  dbl_s[8 * 52];                       //  1.7 KB
    __shared__ float4 cw_s[512];                           //  8.0 KB
    __shared__ float  cb_s[512];                           //  2.0 KB
    int m0 = bid * LCH;

    // ---- stage x rows m0-3 .. m0+7 (clamp row<0) + conv weights ----
    cw_s[t] = *(const float4*)(cwL + t * 4);
    cb_s[t] = cbL[t];
    for (int i = t; i < 11 * 64; i += 512) {
        int r = i >> 6, c = (i & 63) * 4;
        int grow = m0 - 3 + r; if (grow < 0) grow = 0;
        float4 v = *(const float4*)(xin + (size_t)grow * D_MODEL + c);
        *(float4*)&xs[r * XS_STR + c] = v;
    }
    __syncthreads();

    // ---- LayerNorm, 11 rows x 32 threads ----
    if (t < 11 * 32) {
        int r = t >> 5, ci = t & 31;
        float s = 0.f, sq = 0.f;
        #pragma unroll
        for (int k = 0; k < 8; k++) {
            float v = xs[r * XS_STR + ci + 32 * k];
            s += v; sq += v * v;
        }
        #pragma unroll
        for (int off = 1; off < 32; off <<= 1) {
            s  += __shfl_xor(s, off, 32);
            sq += __shfl_xor(sq, off, 32);
        }
        float mu  = s * (1.0f / 256.f);
        float var = sq * (1.0f / 256.f) - mu * mu;
        float rst = rsqrtf(var + 1e-5f);
        #pragma unroll
        for (int k = 0; k < 8; k++) {
            int c = ci + 32 * k;
            float v = (xs[r * XS_STR + c] - mu) * rst * lnwL[c] + lnbL[c];
            hs[r * HS_STR + c] = f2bf(v);
        }
    }
    __syncthreads();

    // ---- in_proj MFMA (f split 4+4, 2-deep weight dbuf) + fused conv ----
    {
        bf16x8 af[8];
        #pragma unroll
        for (int k8 = 0; k8 < 8; k8++)
            af[k8] = *(const bf16x8*)&hs[l15 * HS_STR + quad * 8 + k8 * 32];
        const ushort* wb = ipwT + (size_t)w * 64 * 512 + l15 * 32 + quad * 8;

        #pragma unroll
        for (int half = 0; half < 2; half++) {
            const ushort* wh = wb + (size_t)half * 4 * 8 * 512;
            f32x4 acc[4];
            #pragma unroll
            for (int f = 0; f < 4; f++) acc[f] = (f32x4){0.f, 0.f, 0.f, 0.f};
            bf16x8 bA[4], bB[4];
            #pragma unroll
            for (int f = 0; f < 4; f++) bA[f] = *(const bf16x8*)(wh + (f * 8) * 512);
            #pragma unroll
            for (int k8 = 0; k8 < 8; k8++) {
                bf16x8* cur = (k8 & 1) ? bB : bA;
                bf16x8* nxt = (k8 & 1) ? bA : bB;
                if (k8 < 7) {
                    #pragma unroll
                    for (int f = 0; f < 4; f++)
                        nxt[f] = *(const bf16x8*)(wh + (f * 8 + k8 + 1) * 512);
                }
                #pragma unroll
                for (int f = 0; f < 4; f++)
                    acc[f] = __builtin_amdgcn_mfma_f32_16x16x32_bf16(af[k8], cur[f], acc[f], 0, 0, 0);
            }

            if (w < 4) {
                // fused conv (R9-verified): xi rows live in acc across quads.
                #pragma unroll
                for (int f = 0; f < 4; f++) {
                    int n = w * 128 + (half * 4 + f) * 16 + l15;
                    float x0 = acc[f][0], x1 = acc[f][1], x2 = acc[f][2], x3 = acc[f][3];
                    float p1 = __shfl_up(x1, 16);
                    float p2 = __shfl_up(x2, 16);
                    float p3 = __shfl_up(x3, 16);
                    float4 cwv = cw_s[n];
                    float cbv = cb_s[n];
                    int jb = quad * 4 - 3;
                    #define EMIT(JOFF, T0, T1, T2, T3)                          \
                    {   int j = jb + (JOFF);                                    \
                        if (j >= 0 && j < 8) {                                  \
                            int l = (m0 + j) & (SEQLEN - 1);                    \
                            float s = cbv;                                      \
                            if (l >= 3) s = fmaf(cwv.x, (T0), s);               \
                            if (l >= 2) s = fmaf(cwv.y, (T1), s);               \
                            if (l >= 1) s = fmaf(cwv.z, (T2), s);               \
                            s = fmaf(cwv.w, (T3), s);                           \
                            xc_s[j * XC_STR + n] = f2bf(silu(s));               \
                        }                                                       \
                    }
                    EMIT(0, p1, p2, p3, x0)
                    EMIT(1, p2, p3, x0, x1)
                    EMIT(2, p3, x0, x1, x2)
                    EMIT(3, x0, x1, x2, x3)
                    #undef EMIT
                }
            } else {
                // z path: n >= 512, valid rows rl 3..10 -> z_s rows 0..7 (LDS)
                #pragma unroll
                for (int f = 0; f < 4; f++) {
                    int n = w * 128 + (half * 4 + f) * 16 + l15;
                    #pragma unroll
                    for (int r2 = 0; r2 < 4; r2++) {
                        int rl = quad * 4 + r2;
                        if (rl >= 3 && rl < 11)
                            z_s[(rl - 3) * 512 + (n - 512)] = f2bf(silu(acc[f][r2]));
                    }
                }
            }
        }
    }

    // ---- hoist scan params + compute a[] (overlaps x_proj phase) ----
    float a[16], wdp[16];
    {
        float al[16];
        *(float4*)&al[0]   = *(const float4*)(alogL + (size_t)t * 16 + 0);
        *(float4*)&al[4]   = *(const float4*)(alogL + (size_t)t * 16 + 4);
        *(float4*)&al[8]   = *(const float4*)(alogL + (size_t)t * 16 + 8);
        *(float4*)&al[12]  = *(const float4*)(alogL + (size_t)t * 16 + 12);
        #pragma unroll
        for (int n = 0; n < 16; n++) a[n] = -__expf(al[n]);
    }
    *(float4*)&wdp[0]  = *(const float4*)(dpwL + (size_t)t * 16 + 0);
    *(float4*)&wdp[4]  = *(const float4*)(dpwL + (size_t)t * 16 + 4);
    *(float4*)&wdp[8]  = *(const float4*)(dpwL + (size_t)t * 16 + 8);
    *(float4*)&wdp[12] = *(const float4*)(dpwL + (size_t)t * 16 + 12);
    float bias = dpbL[t];
    __syncthreads();

    // ---- x_proj MFMA (waves 0-2) ∥ coalesced xcB/zsB drain (waves 3-7) ----
    if (w < 3) {
        const ushort* wb = xpwT + (size_t)w * 16 * 512 + l15 * 32 + quad * 8;
        bf16x8 bw[16];
        #pragma unroll
        for (int k8 = 0; k8 < 16; k8++)
            bw[k8] = *(const bf16x8*)(wb + k8 * 512);
        f32x4 acc = (f32x4){0.f, 0.f, 0.f, 0.f};
        #pragma unroll
        for (int k8 = 0; k8 < 16; k8++) {
            bf16x8 af = *(const bf16x8*)&xc_s[l15 * XC_STR + quad * 8 + k8 * 32];
            acc = __builtin_amdgcn_mfma_f32_16x16x32_bf16(af, bw[k8], acc, 0, 0, 0);
        }
        int n = w * 16 + l15;
        #pragma unroll
        for (int r2 = 0; r2 < 4; r2++) {
            int rl = quad * 4 + r2;
            if (rl < LCH) {
                dbl_s[rl * 52 + n] = acc[r2];
                dbl[(size_t)(m0 + rl) * 48 + n] = acc[r2];
            }
        }
    } else {
        // 320 idle threads stream 2 x 8 rows x 512 ushorts as ushort4.
        int ti = t - 192;
        for (int i = ti; i < 2048; i += 320) {
            int arr = i >> 10, rem = i & 1023;
            int row = rem >> 7, c4 = (rem & 127) * 4;
            if (arr == 0) {
                ushort4 v = *(const ushort4*)&xc_s[row * XC_STR + c4];
                *(ushort4*)(xcB + (size_t)(m0 + row) * D_INNER + c4) = v;
            } else {
                ushort4 v = *(const ushort4*)&z_s[row * 512 + c4];
                *(ushort4*)(zsB + (size_t)(m0 + row) * D_INNER + c4) = v;
            }
        }
    }
    __syncthreads();

    // ---- scan_sum (d = t, all 512 threads), 8 serial steps ----
    {
        float h[16];
        #pragma unroll
        for (int n = 0; n < 16; n++) h[n] = 0.f;
        float sd = 0.f;
        for (int j = 0; j < LCH; j++) {
            const float* dp = &dbl_s[j * 52];
            float d0 = 0.f, d1 = 0.f;
            #pragma unroll
            for (int r2 = 0; r2 < 8; r2++) {
                d0 = fmaf(dp[r2], wdp[r2], d0);
                d1 = fmaf(dp[8 + r2], wdp[8 + r2], d1);
            }
            float dl = softplus_f(bias + d0 + d1);
            float xv = bf2f(xc_s[j * XC_STR + t]);
            float u = dl * xv;
            sd += dl;
            #pragma unroll
            for (int n = 0; n < 16; n++)
                h[n] = fmaf(__expf(dl * a[n]), h[n], dp[16 + n] * u);
        }
        size_t sbase = (size_t)bid * 16 * D_INNER + t;
        #pragma unroll
        for (int n = 0; n < 16; n++) Ssum[sbase + (size_t)n * D_INNER] = h[n];
        sdsum[(size_t)bid * D_INNER + t] = sd;
    }
}

// ---------------------------------------------------------------------------
// k_comb: two-level exclusive prefix over 512 chunk summaries. Grid 512x512.
// Only EVEN chunks' prefixes are stored (k_back consumes chunk 2*bid only).
// ---------------------------------------------------------------------------
__global__ __launch_bounds__(512, 4) void k_comb(
    const float* __restrict__ alogL, const float* __restrict__ sdsum,
    float* __restrict__ Ssum)
{
    const int t = threadIdx.x, bid = blockIdx.x;
    __shared__ float S_l[32][17], sd_l[32][17];
    int ch32 = t & 31, seg = t >> 5;
    int chain = bid * 32 + ch32;
    int d = chain & 511;
    int n = (chain >> 9) & 15;
    int b = chain >> 13;
    float a = -__expf(alogL[(size_t)d * 16 + n]);
    int c0 = b * CPB + seg * 16;

    float s_r[16], sd_r[16];
    float S = 0.f, sdt = 0.f;
    #pragma unroll
    for (int j = 0; j < 16; j++) {
        size_t c = (size_t)(c0 + j);
        float s  = Ssum[(c * 16 + n) * D_INNER + d];
        float sd = sdsum[c * D_INNER + d];
        s_r[j] = s; sd_r[j] = sd;
        S = fmaf(__expf(a * sd), S, s);
        sdt += sd;
    }
    S_l[ch32][seg] = S;
    sd_l[ch32][seg] = sdt;
    __syncthreads();

    if (t < 32) {
        float hi = 0.f;
        #pragma unroll
        for (int g = 0; g < 16; g++) {
            float Sv = S_l[t][g], sdv = sd_l[t][g];
            S_l[t][g] = hi;
            hi = fmaf(__expf(a * sdv), hi, Sv);
        }
    }
    __syncthreads();

    float hi = S_l[ch32][seg];
    #pragma unroll
    for (int j = 0; j < 16; j++) {
        size_t c = (size_t)(c0 + j);
        if (!(j & 1))   // c0 even, so c even iff j even
            Ssum[(c * 16 + n) * D_INNER + d] = hi;
        hi = fmaf(__expf(a * sd_r[j]), hi, s_r[j]);
    }
}

// ---------------------------------------------------------------------------
// k_back: TWO chunks (16 rows) per block. Grid 256 x 512.
// Rescan continues through both chunks; only even chunk's Ssum read.
// All loads hoisted/batched; out_proj full-density 16-row tiles.
// ---------------------------------------------------------------------------
__global__ __launch_bounds__(512, 2) void k_back(
    const float* __restrict__ dbl, const ushort* __restrict__ xcB,
    const ushort* __restrict__ zsB, const float* __restrict__ Ssum,
    const float* __restrict__ dpwL, const float* __restrict__ dpbL,
    const float* __restrict__ alogL, const float* __restrict__ dparL,
    const ushort* __restrict__ opwT, const float* __restrict__ xin,
    float* __restrict__ xout)
{
    const int t = threadIdx.x, bid = blockIdx.x;
    const int lane = t & 63, w = t >> 6, l15 = lane & 15, quad = lane >> 4;
    __shared__ ushort yy_s[16 * XC_STR];   // 16.6 KB, all 16 rows valid
    __shared__ float  dbl_l[16 * 48];      //  3.0 KB
    int m0 = bid * 16;

    // ---- stage both chunks' dbl rows into LDS ----
    for (int i = t; i < 16 * 48; i += 512) dbl_l[i] = dbl[(size_t)m0 * 48 + i];

    // ---- hoist ALL global inputs for the rescan (batched issue) ----
    ushort xcv[16], zsv[16];
    #pragma unroll
    for (int j = 0; j < 16; j++) {
        size_t rb = (size_t)(m0 + j) * D_INNER + t;
        xcv[j] = xcB[rb];
        zsv[j] = zsB[rb];
    }
    float h[16];
    {
        size_t sbase = ((size_t)(2 * bid) * 16) * D_INNER + t;  // even chunk
        #pragma unroll
        for (int n = 0; n < 16; n++) h[n] = Ssum[sbase + (size_t)n * D_INNER];
    }
    float a[16], wdp[16];
    {
        float al[16];
        *(float4*)&al[0]  = *(const float4*)(alogL + (size_t)t * 16 + 0);
        *(float4*)&al[4]  = *(const float4*)(alogL + (size_t)t * 16 + 4);
        *(float4*)&al[8]  = *(const float4*)(alogL + (size_t)t * 16 + 8);
        *(float4*)&al[12] = *(const float4*)(alogL + (size_t)t * 16 + 12);
        #pragma unroll
        for (int n = 0; n < 16; n++) a[n] = -__expf(al[n]);
    }
    *(float4*)&wdp[0]  = *(const float4*)(dpwL + (size_t)t * 16 + 0);
    *(float4*)&wdp[4]  = *(const float4*)(dpwL + (size_t)t * 16 + 4);
    *(float4*)&wdp[8]  = *(const float4*)(dpwL + (size_t)t * 16 + 8);
    *(float4*)&wdp[12] = *(const float4*)(dpwL + (size_t)t * 16 + 12);
    float bias = dpbL[t];
    float Dd = dparL[t];
    __syncthreads();

    // ---- rescan 16 rows, d = t ----
    for (int j = 0; j < 16; j++) {
        const float* dp = &dbl_l[j * 48];
        float d0 = 0.f, d1 = 0.f;
        #pragma unroll
        for (int r2 = 0; r2 < 8; r2++) {
            d0 = fmaf(dp[r2], wdp[r2], d0);
            d1 = fmaf(dp[8 + r2], wdp[8 + r2], d1);
        }
        float dl = softplus_f(bias + d0 + d1);
        float xv = bf2f(xcv[j]);
        float gate = bf2f(zsv[j]);
        float u = dl * xv;
        float y0 = 0.f, y1 = 0.f, y2 = 0.f, y3 = 0.f;
        #pragma unroll
        for (int q = 0; q < 4; q++) {
            h[4 * q + 0] = fmaf(__expf(dl * a[4 * q + 0]), h[4 * q + 0], dp[16 + 4 * q + 0] * u);
            h[4 * q + 1] = fmaf(__expf(dl * a[4 * q + 1]), h[4 * q + 1], dp[16 + 4 * q + 1] * u);
            h[4 * q + 2] = fmaf(__expf(dl * a[4 * q + 2]), h[4 * q + 2], dp[16 + 4 * q + 2] * u);
            h[4 * q + 3] = fmaf(__expf(dl * a[4 * q + 3]), h[4 * q + 3], dp[16 + 4 * q + 3] * u);
            y0 = fmaf(h[4 * q + 0], dp[32 + 4 * q + 0], y0);
            y1 = fmaf(h[4 * q + 1], dp[32 + 4 * q + 1], y1);
            y2 = fmaf(h[4 * q + 2], dp[32 + 4 * q + 2], y2);
            y3 = fmaf(h[4 * q + 3], dp[32 + 4 * q + 3], y3);
        }
        float y = (y0 + y1) + (y2 + y3) + xv * Dd;
        yy_s[j * XC_STR + t] = f2bf(y * gate);
    }
    __syncthreads();

    // ---- out_proj MFMA + residual: full 16-row tiles, 2-deep ping-pong ----
    {
        const ushort* wb = opwT + (size_t)w * 2 * 16 * 512 + l15 * 32 + quad * 8;
        f32x4 acc0 = (f32x4){0.f, 0.f, 0.f, 0.f};
        f32x4 acc1 = (f32x4){0.f, 0.f, 0.f, 0.f};
        bf16x8 bA0 = *(const bf16x8*)(wb + 0 * 512);
        bf16x8 bA1 = *(const bf16x8*)(wb + 16 * 512);
        bf16x8 bB0, bB1;
        #pragma unroll
        for (int k8 = 0; k8 < 16; k8++) {
            if (k8 < 15) {
                if (k8 & 1) { bA0 = *(const bf16x8*)(wb + (k8 + 1) * 512);
                              bA1 = *(const bf16x8*)(wb + (16 + k8 + 1) * 512); }
                else        { bB0 = *(const bf16x8*)(wb + (k8 + 1) * 512);
                              bB1 = *(const bf16x8*)(wb + (16 + k8 + 1) * 512); }
            }
            bf16x8 af = *(const bf16x8*)&yy_s[l15 * XC_STR + quad * 8 + k8 * 32];
            bf16x8 c0 = (k8 & 1) ? bB0 : bA0;
            bf16x8 c1 = (k8 & 1) ? bB1 : bA1;
            acc0 = __builtin_amdgcn_mfma_f32_16x16x32_bf16(af, c0, acc0, 0, 0, 0);
            acc1 = __builtin_amdgcn_mfma_f32_16x16x32_bf16(af, c1, acc1, 0, 0, 0);
        }
        #pragma unroll
        for (int f = 0; f < 2; f++) {
            int n = w * 32 + f * 16 + l15;
            const f32x4& acc = (f == 0) ? acc0 : acc1;
            #pragma unroll
            for (int r2 = 0; r2 < 4; r2++) {
                int row = m0 + quad * 4 + r2;
                xout[(size_t)row * D_MODEL + n] =
                    acc[r2] + xin[(size_t)row * D_MODEL + n];
            }
        }
    }
}

// ---------------------------------------------------------------------------
// Launch. Inter-layer activation routed through d_out.
// ---------------------------------------------------------------------------
extern "C" void kernel_launch(void* const* d_in, const int* in_sizes, int n_in,
                              void* d_out, int out_size, void* d_ws, size_t ws_size,
                              hipStream_t stream)
{
    const float* x    = (const float*)d_in[0];
    const float* lnw  = (const float*)d_in[1];
    const float* lnb  = (const float*)d_in[2];
    const float* ipw  = (const float*)d_in[3];
    const float* cw   = (const float*)d_in[4];
    const float* cb   = (const float*)d_in[5];
    const float* xpw  = (const float*)d_in[6];
    const float* dpw  = (const float*)d_in[7];
    const float* dpb  = (const float*)d_in[8];
    const float* alog = (const float*)d_in[9];
    const float* dpar = (const float*)d_in[10];
    const float* opw  = (const float*)d_in[11];
    float* out = (float*)d_out;

    char* p = (char*)d_ws;
    auto alloc = [&](size_t bytes) { char* r = p; p += (bytes + 255) & ~(size_t)255; return r; };
    ushort* zsB   = (ushort*)alloc((size_t)MROWS * D_INNER * 2);
    ushort* xcB   = (ushort*)alloc((size_t)MROWS * D_INNER * 2);
    float*  dbl   = (float*)alloc((size_t)MROWS * 48 * 4);
    float*  Ssum  = (float*)alloc((size_t)NCH * 16 * D_INNER * 4);
    float*  sdsum = (float*)alloc((size_t)NCH * D_INNER * 4);
    ushort* ipwT  = (ushort*)alloc((size_t)DEPTH * 262144 * 2);
    ushort* xpwT  = (ushort*)alloc((size_t)DEPTH * 24576 * 2);
    ushort* opwT  = (ushort*)alloc((size_t)DEPTH * 131072 * 2);

    k_cvt<<<512, 256, 0, stream>>>(ipw, xpw, opw, ipwT, xpwT, opwT);

    for (int lyr = 0; lyr < DEPTH; lyr++) {
        const float* xin = (lyr == 0) ? x : out;
        float* xout = out;
        const float* alogL = alog + (size_t)lyr * D_INNER * D_STATE;
        const float* dpwL  = dpw + (size_t)lyr * D_INNER * DT_RANK;
        const float* dpbL  = dpb + lyr * D_INNER;

        k_front<<<NCH, 512, 0, stream>>>(
            xin, lnw + lyr * D_MODEL, lnb + lyr * D_MODEL,
            ipwT + (size_t)lyr * 262144,
            cw + (size_t)lyr * D_INNER * D_CONV, cb + lyr * D_INNER,
            xpwT + (size_t)lyr * 24576, dpwL, dpbL, alogL,
            zsB, xcB, dbl, Ssum, sdsum);

        k_comb<<<512, 512, 0, stream>>>(alogL, sdsum, Ssum);

        k_back<<<NCH / 2, 512, 0, stream>>>(
            dbl, xcB, zsB, Ssum, dpwL, dpbL, alogL,
            dpar + lyr * D_INNER,
            opwT + (size_t)lyr * 131072, xin, xout);
    }
}

// Round 12
// 201.442 us; speedup vs baseline: 1.0437x; 1.0084x over previous
//
#include <hip/hip_runtime.h>
#include <hip/hip_bf16.h>
#include <math.h>

// Problem constants
#define D_MODEL 256
#define DEPTH 2
#define D_INNER 512
#define D_STATE 16
#define D_CONV 4
#define DT_RANK 16
#define BATCH 2
#define SEQLEN 2048
#define MROWS (BATCH * SEQLEN)   // 4096

#define LCH 8     // rows per chunk (front)
#define NCH 512   // total chunks
#define CPB 256   // chunks per batch

typedef __attribute__((ext_vector_type(8))) short bf16x8;
typedef __attribute__((ext_vector_type(4))) float f32x4;

__device__ __forceinline__ float silu(float v) {
    return v / (1.0f + __expf(-v));
}

__device__ __forceinline__ ushort f2bf(float f) {
    union { float f; unsigned u; } v; v.f = f;
    unsigned r = v.u + 0x7FFFu + ((v.u >> 16) & 1u);
    return (ushort)(r >> 16);
}

__device__ __forceinline__ float bf2f(ushort u) {
    union { unsigned u; float f; } v; v.u = ((unsigned)u) << 16;
    return v.f;
}

__device__ __forceinline__ float softplus_f(float x) {
    return (x > 20.f) ? x : __logf(1.f + __expf(x));
}

#define HS_STR 264   // ushort stride, bf16 LN output (16 rows, 11 valid)
#define XC_STR 520   // ushort stride, xc/yy LDS tiles

// ---------------------------------------------------------------------------
// k_cvt: f32 -> bf16 AND re-layout to MFMA tile-major: per (nt,kt) a 1-KB
// tile [16 r][32 c] so one wave weight-load = one coalesced 1-KB segment.
// ---------------------------------------------------------------------------
__global__ __launch_bounds__(256) void k_cvt(
    const float* __restrict__ ipw, const float* __restrict__ xpw,
    const float* __restrict__ opw, ushort* __restrict__ ipwT,
    ushort* __restrict__ xpwT, ushort* __restrict__ opwT)
{
    size_t tid = (size_t)blockIdx.x * 256 + threadIdx.x;
    {   // ipw: [2][1024 n][256 k] -> per layer [64 nt][8 kt][16 r][32 c]
        int lyr = (int)(tid >> 16), rem = (int)(tid & 65535);
        int n = rem >> 6, k = (rem & 63) * 4;
        float4 v = *(const float4*)(ipw + ((size_t)lyr * 1024 + n) * 256 + k);
        int nt = n >> 4, r = n & 15, kt = k >> 5, c = k & 31;
        ushort4 o = { f2bf(v.x), f2bf(v.y), f2bf(v.z), f2bf(v.w) };
        *(ushort4*)(ipwT + (size_t)lyr * 262144 + (nt * 8 + kt) * 512 + r * 32 + c) = o;
    }
    if (tid < 12288) {   // xpw: [2][48][512] -> per layer [3 nt][16 kt] tiles
        int lyr = (int)(tid / 6144), rem = (int)(tid % 6144);
        int n = rem >> 7, k = (rem & 127) * 4;
        float4 v = *(const float4*)(xpw + ((size_t)lyr * 48 + n) * 512 + k);
        int nt = n >> 4, r = n & 15, kt = k >> 5, c = k & 31;
        ushort4 o = { f2bf(v.x), f2bf(v.y), f2bf(v.z), f2bf(v.w) };
        *(ushort4*)(xpwT + (size_t)lyr * 24576 + (nt * 16 + kt) * 512 + r * 32 + c) = o;
    }
    if (tid < 65536) {   // opw: [2][256][512] -> per layer [16 nt][16 kt]
        int lyr = (int)(tid >> 15), rem = (int)(tid & 32767);
        int n = rem >> 7, k = (rem & 127) * 4;
        float4 v = *(const float4*)(opw + ((size_t)lyr * 256 + n) * 512 + k);
        int nt = n >> 4, r = n & 15, kt = k >> 5, c = k & 31;
        ushort4 o = { f2bf(v.x), f2bf(v.y), f2bf(v.z), f2bf(v.w) };
        *(ushort4*)(opwT + (size_t)lyr * 131072 + (nt * 16 + kt) * 512 + r * 32 + c) = o;
    }
}

// ---------------------------------------------------------------------------
// k_front: 8-row chunk, 4 phases / 3 barriers, LDS 34.9 KB -> 4 blocks/CU.
//   LN (direct global reads, no staging) | in_proj MFMA + in-register conv
//   (conv weights straight from L2) | x_proj MFMA waves 0-2 ∥ coalesced
//   xcB/zsB drain waves 3-7 | scan_sum.
// Grid 512 x 512.
// ---------------------------------------------------------------------------
__global__ __launch_bounds__(512, 4) void k_front(
    const float* __restrict__ xin, const float* __restrict__ lnwL,
    const float* __restrict__ lnbL, const ushort* __restrict__ ipwT,
    const float* __restrict__ cwL, const float* __restrict__ cbL,
    const ushort* __restrict__ xpwT, const float* __restrict__ dpwL,
    const float* __restrict__ dpbL, const float* __restrict__ alogL,
    ushort* __restrict__ zsB, ushort* __restrict__ xcB,
    float* __restrict__ dbl, float* __restrict__ Ssum,
    float* __restrict__ sdsum)
{
    const int t = threadIdx.x, bid = blockIdx.x;
    const int lane = t & 63, w = t >> 6, l15 = lane & 15, quad = lane >> 4;
    __shared__ ushort hs[16 * HS_STR];                     //  8.4 KB
    __shared__ __align__(16) ushort xc_s[16 * XC_STR];     // 16.6 KB
    __shared__ __align__(16) ushort z_s[8 * 512];          //  8.2 KB
    __shared__ float  dbl_s[8 * 52];                       //  1.7 KB
    int m0 = bid * LCH;

    // ---- LayerNorm: 11 rows x 32 threads, direct global loads ----
    if (t < 11 * 32) {
        int r = t >> 5, ci = t & 31;
        int grow = m0 - 3 + r; if (grow < 0) grow = 0;
        const float* xr = xin + (size_t)grow * D_MODEL + ci * 8;
        float4 v0 = *(const float4*)xr;
        float4 v1 = *(const float4*)(xr + 4);
        float vals[8] = { v0.x, v0.y, v0.z, v0.w, v1.x, v1.y, v1.z, v1.w };
        float s = 0.f, sq = 0.f;
        #pragma unroll
        for (int k = 0; k < 8; k++) { s += vals[k]; sq += vals[k] * vals[k]; }
        #pragma unroll
        for (int off = 1; off < 32; off <<= 1) {
            s  += __shfl_xor(s, off, 32);
            sq += __shfl_xor(sq, off, 32);
        }
        float mu  = s * (1.0f / 256.f);
        float var = sq * (1.0f / 256.f) - mu * mu;
        float rst = rsqrtf(var + 1e-5f);
        #pragma unroll
        for (int k = 0; k < 8; k++) {
            int c = ci * 8 + k;
            hs[r * HS_STR + c] = f2bf((vals[k] - mu) * rst * lnwL[c] + lnbL[c]);
        }
    }
    __syncthreads();

    // ---- in_proj MFMA (f split 4+4, 2-deep weight dbuf) + fused conv ----
    {
        bf16x8 af[8];
        #pragma unroll
        for (int k8 = 0; k8 < 8; k8++)
            af[k8] = *(const bf16x8*)&hs[l15 * HS_STR + quad * 8 + k8 * 32];
        const ushort* wb = ipwT + (size_t)w * 64 * 512 + l15 * 32 + quad * 8;

        #pragma unroll
        for (int half = 0; half < 2; half++) {
            const ushort* wh = wb + (size_t)half * 4 * 8 * 512;
            f32x4 acc[4];
            #pragma unroll
            for (int f = 0; f < 4; f++) acc[f] = (f32x4){0.f, 0.f, 0.f, 0.f};
            bf16x8 bA[4], bB[4];
            #pragma unroll
            for (int f = 0; f < 4; f++) bA[f] = *(const bf16x8*)(wh + (f * 8) * 512);
            #pragma unroll
            for (int k8 = 0; k8 < 8; k8++) {
                bf16x8* cur = (k8 & 1) ? bB : bA;
                bf16x8* nxt = (k8 & 1) ? bA : bB;
                if (k8 < 7) {
                    #pragma unroll
                    for (int f = 0; f < 4; f++)
                        nxt[f] = *(const bf16x8*)(wh + (f * 8 + k8 + 1) * 512);
                }
                #pragma unroll
                for (int f = 0; f < 4; f++)
                    acc[f] = __builtin_amdgcn_mfma_f32_16x16x32_bf16(af[k8], cur[f], acc[f], 0, 0, 0);
            }

            if (w < 4) {
                // fused conv (R9-verified): xi rows live in acc across quads;
                // conv weights straight from L2 (16 consecutive float4/quad).
                #pragma unroll
                for (int f = 0; f < 4; f++) {
                    int n = w * 128 + (half * 4 + f) * 16 + l15;
                    float x0 = acc[f][0], x1 = acc[f][1], x2 = acc[f][2], x3 = acc[f][3];
                    float p1 = __shfl_up(x1, 16);
                    float p2 = __shfl_up(x2, 16);
                    float p3 = __shfl_up(x3, 16);
                    float4 cwv = *(const float4*)(cwL + n * 4);
                    float cbv = cbL[n];
                    int jb = quad * 4 - 3;
                    #define EMIT(JOFF, T0, T1, T2, T3)                          \
                    {   int j = jb + (JOFF);                                    \
                        if (j >= 0 && j < 8) {                                  \
                            int l = (m0 + j) & (SEQLEN - 1);                    \
                            float s = cbv;                                      \
                            if (l >= 3) s = fmaf(cwv.x, (T0), s);               \
                            if (l >= 2) s = fmaf(cwv.y, (T1), s);               \
                            if (l >= 1) s = fmaf(cwv.z, (T2), s);               \
                            s = fmaf(cwv.w, (T3), s);                           \
                            xc_s[j * XC_STR + n] = f2bf(silu(s));               \
                        }                                                       \
                    }
                    EMIT(0, p1, p2, p3, x0)
                    EMIT(1, p2, p3, x0, x1)
                    EMIT(2, p3, x0, x1, x2)
                    EMIT(3, x0, x1, x2, x3)
                    #undef EMIT
                }
            } else {
                // z path: n >= 512, valid rows rl 3..10 -> z_s rows 0..7 (LDS)
                #pragma unroll
                for (int f = 0; f < 4; f++) {
                    int n = w * 128 + (half * 4 + f) * 16 + l15;
                    #pragma unroll
                    for (int r2 = 0; r2 < 4; r2++) {
                        int rl = quad * 4 + r2;
                        if (rl >= 3 && rl < 11)
                            z_s[(rl - 3) * 512 + (n - 512)] = f2bf(silu(acc[f][r2]));
                    }
                }
            }
        }
    }

    // ---- hoist scan params + compute a[] (overlaps x_proj phase) ----
    float a[16], wdp[16];
    {
        float al[16];
        *(float4*)&al[0]   = *(const float4*)(alogL + (size_t)t * 16 + 0);
        *(float4*)&al[4]   = *(const float4*)(alogL + (size_t)t * 16 + 4);
        *(float4*)&al[8]   = *(const float4*)(alogL + (size_t)t * 16 + 8);
        *(float4*)&al[12]  = *(const float4*)(alogL + (size_t)t * 16 + 12);
        #pragma unroll
        for (int n = 0; n < 16; n++) a[n] = -__expf(al[n]);
    }
    *(float4*)&wdp[0]  = *(const float4*)(dpwL + (size_t)t * 16 + 0);
    *(float4*)&wdp[4]  = *(const float4*)(dpwL + (size_t)t * 16 + 4);
    *(float4*)&wdp[8]  = *(const float4*)(dpwL + (size_t)t * 16 + 8);
    *(float4*)&wdp[12] = *(const float4*)(dpwL + (size_t)t * 16 + 12);
    float bias = dpbL[t];
    __syncthreads();

    // ---- x_proj MFMA (waves 0-2) ∥ coalesced xcB/zsB drain (waves 3-7) ----
    if (w < 3) {
        const ushort* wb = xpwT + (size_t)w * 16 * 512 + l15 * 32 + quad * 8;
        bf16x8 bw[16];
        #pragma unroll
        for (int k8 = 0; k8 < 16; k8++)
            bw[k8] = *(const bf16x8*)(wb + k8 * 512);
        f32x4 acc = (f32x4){0.f, 0.f, 0.f, 0.f};
        #pragma unroll
        for (int k8 = 0; k8 < 16; k8++) {
            bf16x8 af = *(const bf16x8*)&xc_s[l15 * XC_STR + quad * 8 + k8 * 32];
            acc = __builtin_amdgcn_mfma_f32_16x16x32_bf16(af, bw[k8], acc, 0, 0, 0);
        }
        int n = w * 16 + l15;
        #pragma unroll
        for (int r2 = 0; r2 < 4; r2++) {
            int rl = quad * 4 + r2;
            if (rl < LCH) {
                dbl_s[rl * 52 + n] = acc[r2];
                dbl[(size_t)(m0 + rl) * 48 + n] = acc[r2];
            }
        }
    } else {
        // 320 idle threads stream 2 x 8 rows x 512 ushorts as ushort4.
        int ti = t - 192;
        for (int i = ti; i < 2048; i += 320) {
            int arr = i >> 10, rem = i & 1023;
            int row = rem >> 7, c4 = (rem & 127) * 4;
            if (arr == 0) {
                ushort4 v = *(const ushort4*)&xc_s[row * XC_STR + c4];
                *(ushort4*)(xcB + (size_t)(m0 + row) * D_INNER + c4) = v;
            } else {
                ushort4 v = *(const ushort4*)&z_s[row * 512 + c4];
                *(ushort4*)(zsB + (size_t)(m0 + row) * D_INNER + c4) = v;
            }
        }
    }
    __syncthreads();

    // ---- scan_sum (d = t, all 512 threads), 8 serial steps ----
    {
        float h[16];
        #pragma unroll
        for (int n = 0; n < 16; n++) h[n] = 0.f;
        float sd = 0.f;
        for (int j = 0; j < LCH; j++) {
            const float* dp = &dbl_s[j * 52];
            float d0 = 0.f, d1 = 0.f;
            #pragma unroll
            for (int r2 = 0; r2 < 8; r2++) {
                d0 = fmaf(dp[r2], wdp[r2], d0);
                d1 = fmaf(dp[8 + r2], wdp[8 + r2], d1);
            }
            float dl = softplus_f(bias + d0 + d1);
            float xv = bf2f(xc_s[j * XC_STR + t]);
            float u = dl * xv;
            sd += dl;
            #pragma unroll
            for (int n = 0; n < 16; n++)
                h[n] = fmaf(__expf(dl * a[n]), h[n], dp[16 + n] * u);
        }
        size_t sbase = (size_t)bid * 16 * D_INNER + t;
        #pragma unroll
        for (int n = 0; n < 16; n++) Ssum[sbase + (size_t)n * D_INNER] = h[n];
        sdsum[(size_t)bid * D_INNER + t] = sd;
    }
}

// ---------------------------------------------------------------------------
// k_comb: two-level exclusive prefix over 512 chunk summaries. Grid 512x512.
// Only EVEN chunks' prefixes are stored (k_back consumes chunk 2*bid only).
// ---------------------------------------------------------------------------
__global__ __launch_bounds__(512, 4) void k_comb(
    const float* __restrict__ alogL, const float* __restrict__ sdsum,
    float* __restrict__ Ssum)
{
    const int t = threadIdx.x, bid = blockIdx.x;
    __shared__ float S_l[32][17], sd_l[32][17];
    int ch32 = t & 31, seg = t >> 5;
    int chain = bid * 32 + ch32;
    int d = chain & 511;
    int n = (chain >> 9) & 15;
    int b = chain >> 13;
    float a = -__expf(alogL[(size_t)d * 16 + n]);
    int c0 = b * CPB + seg * 16;

    float s_r[16], sd_r[16];
    float S = 0.f, sdt = 0.f;
    #pragma unroll
    for (int j = 0; j < 16; j++) {
        size_t c = (size_t)(c0 + j);
        float s  = Ssum[(c * 16 + n) * D_INNER + d];
        float sd = sdsum[c * D_INNER + d];
        s_r[j] = s; sd_r[j] = sd;
        S = fmaf(__expf(a * sd), S, s);
        sdt += sd;
    }
    S_l[ch32][seg] = S;
    sd_l[ch32][seg] = sdt;
    __syncthreads();

    if (t < 32) {
        float hi = 0.f;
        #pragma unroll
        for (int g = 0; g < 16; g++) {
            float Sv = S_l[t][g], sdv = sd_l[t][g];
            S_l[t][g] = hi;
            hi = fmaf(__expf(a * sdv), hi, Sv);
        }
    }
    __syncthreads();

    float hi = S_l[ch32][seg];
    #pragma unroll
    for (int j = 0; j < 16; j++) {
        size_t c = (size_t)(c0 + j);
        if (!(j & 1))   // c0 even, so c even iff j even
            Ssum[(c * 16 + n) * D_INNER + d] = hi;
        hi = fmaf(__expf(a * sd_r[j]), hi, s_r[j]);
    }
}

// ---------------------------------------------------------------------------
// k_back: TWO chunks (16 rows) per block. Grid 256 x 512.
// Rescan continues through both chunks; only even chunk's Ssum read.
// All loads hoisted/batched; out_proj full-density 16-row tiles.
// ---------------------------------------------------------------------------
__global__ __launch_bounds__(512, 2) void k_back(
    const float* __restrict__ dbl, const ushort* __restrict__ xcB,
    const ushort* __restrict__ zsB, const float* __restrict__ Ssum,
    const float* __restrict__ dpwL, const float* __restrict__ dpbL,
    const float* __restrict__ alogL, const float* __restrict__ dparL,
    const ushort* __restrict__ opwT, const float* __restrict__ xin,
    float* __restrict__ xout)
{
    const int t = threadIdx.x, bid = blockIdx.x;
    const int lane = t & 63, w = t >> 6, l15 = lane & 15, quad = lane >> 4;
    __shared__ ushort yy_s[16 * XC_STR];   // 16.6 KB, all 16 rows valid
    __shared__ float  dbl_l[16 * 48];      //  3.0 KB
    int m0 = bid * 16;

    // ---- stage both chunks' dbl rows into LDS ----
    for (int i = t; i < 16 * 48; i += 512) dbl_l[i] = dbl[(size_t)m0 * 48 + i];

    // ---- hoist ALL global inputs for the rescan (batched issue) ----
    ushort xcv[16], zsv[16];
    #pragma unroll
    for (int j = 0; j < 16; j++) {
        size_t rb = (size_t)(m0 + j) * D_INNER + t;
        xcv[j] = xcB[rb];
        zsv[j] = zsB[rb];
    }
    float h[16];
    {
        size_t sbase = ((size_t)(2 * bid) * 16) * D_INNER + t;  // even chunk
        #pragma unroll
        for (int n = 0; n < 16; n++) h[n] = Ssum[sbase + (size_t)n * D_INNER];
    }
    float a[16], wdp[16];
    {
        float al[16];
        *(float4*)&al[0]  = *(const float4*)(alogL + (size_t)t * 16 + 0);
        *(float4*)&al[4]  = *(const float4*)(alogL + (size_t)t * 16 + 4);
        *(float4*)&al[8]  = *(const float4*)(alogL + (size_t)t * 16 + 8);
        *(float4*)&al[12] = *(const float4*)(alogL + (size_t)t * 16 + 12);
        #pragma unroll
        for (int n = 0; n < 16; n++) a[n] = -__expf(al[n]);
    }
    *(float4*)&wdp[0]  = *(const float4*)(dpwL + (size_t)t * 16 + 0);
    *(float4*)&wdp[4]  = *(const float4*)(dpwL + (size_t)t * 16 + 4);
    *(float4*)&wdp[8]  = *(const float4*)(dpwL + (size_t)t * 16 + 8);
    *(float4*)&wdp[12] = *(const float4*)(dpwL + (size_t)t * 16 + 12);
    float bias = dpbL[t];
    float Dd = dparL[t];
    __syncthreads();

    // ---- rescan 16 rows, d = t ----
    for (int j = 0; j < 16; j++) {
        const float* dp = &dbl_l[j * 48];
        float d0 = 0.f, d1 = 0.f;
        #pragma unroll
        for (int r2 = 0; r2 < 8; r2++) {
            d0 = fmaf(dp[r2], wdp[r2], d0);
            d1 = fmaf(dp[8 + r2], wdp[8 + r2], d1);
        }
        float dl = softplus_f(bias + d0 + d1);
        float xv = bf2f(xcv[j]);
        float gate = bf2f(zsv[j]);
        float u = dl * xv;
        float y0 = 0.f, y1 = 0.f, y2 = 0.f, y3 = 0.f;
        #pragma unroll
        for (int q = 0; q < 4; q++) {
            h[4 * q + 0] = fmaf(__expf(dl * a[4 * q + 0]), h[4 * q + 0], dp[16 + 4 * q + 0] * u);
            h[4 * q + 1] = fmaf(__expf(dl * a[4 * q + 1]), h[4 * q + 1], dp[16 + 4 * q + 1] * u);
            h[4 * q + 2] = fmaf(__expf(dl * a[4 * q + 2]), h[4 * q + 2], dp[16 + 4 * q + 2] * u);
            h[4 * q + 3] = fmaf(__expf(dl * a[4 * q + 3]), h[4 * q + 3], dp[16 + 4 * q + 3] * u);
            y0 = fmaf(h[4 * q + 0], dp[32 + 4 * q + 0], y0);
            y1 = fmaf(h[4 * q + 1], dp[32 + 4 * q + 1], y1);
            y2 = fmaf(h[4 * q + 2], dp[32 + 4 * q + 2], y2);
            y3 = fmaf(h[4 * q + 3], dp[32 + 4 * q + 3], y3);
        }
        float y = (y0 + y1) + (y2 + y3) + xv * Dd;
        yy_s[j * XC_STR + t] = f2bf(y * gate);
    }
    __syncthreads();

    // ---- out_proj MFMA + residual: full 16-row tiles, 2-deep ping-pong ----
    {
        const ushort* wb = opwT + (size_t)w * 2 * 16 * 512 + l15 * 32 + quad * 8;
        f32x4 acc0 = (f32x4){0.f, 0.f, 0.f, 0.f};
        f32x4 acc1 = (f32x4){0.f, 0.f, 0.f, 0.f};
        bf16x8 bA0 = *(const bf16x8*)(wb + 0 * 512);
        bf16x8 bA1 = *(const bf16x8*)(wb + 16 * 512);
        bf16x8 bB0, bB1;
        #pragma unroll
        for (int k8 = 0; k8 < 16; k8++) {
            if (k8 < 15) {
                if (k8 & 1) { bA0 = *(const bf16x8*)(wb + (k8 + 1) * 512);
                              bA1 = *(const bf16x8*)(wb + (16 + k8 + 1) * 512); }
                else        { bB0 = *(const bf16x8*)(wb + (k8 + 1) * 512);
                              bB1 = *(const bf16x8*)(wb + (16 + k8 + 1) * 512); }
            }
            bf16x8 af = *(const bf16x8*)&yy_s[l15 * XC_STR + quad * 8 + k8 * 32];
            bf16x8 c0 = (k8 & 1) ? bB0 : bA0;
            bf16x8 c1 = (k8 & 1) ? bB1 : bA1;
            acc0 = __builtin_amdgcn_mfma_f32_16x16x32_bf16(af, c0, acc0, 0, 0, 0);
            acc1 = __builtin_amdgcn_mfma_f32_16x16x32_bf16(af, c1, acc1, 0, 0, 0);
        }
        #pragma unroll
        for (int f = 0; f < 2; f++) {
            int n = w * 32 + f * 16 + l15;
            const f32x4& acc = (f == 0) ? acc0 : acc1;
            #pragma unroll
            for (int r2 = 0; r2 < 4; r2++) {
                int row = m0 + quad * 4 + r2;
                xout[(size_t)row * D_MODEL + n] =
                    acc[r2] + xin[(size_t)row * D_MODEL + n];
            }
        }
    }
}

// ---------------------------------------------------------------------------
// Launch. Inter-layer activation routed through d_out.
// ---------------------------------------------------------------------------
extern "C" void kernel_launch(void* const* d_in, const int* in_sizes, int n_in,
                              void* d_out, int out_size, void* d_ws, size_t ws_size,
                              hipStream_t stream)
{
    const float* x    = (const float*)d_in[0];
    const float* lnw  = (const float*)d_in[1];
    const float* lnb  = (const float*)d_in[2];
    const float* ipw  = (const float*)d_in[3];
    const float* cw   = (const float*)d_in[4];
    const float* cb   = (const float*)d_in[5];
    const float* xpw  = (const float*)d_in[6];
    const float* dpw  = (const float*)d_in[7];
    const float* dpb  = (const float*)d_in[8];
    const float* alog = (const float*)d_in[9];
    const float* dpar = (const float*)d_in[10];
    const float* opw  = (const float*)d_in[11];
    float* out = (float*)d_out;

    char* p = (char*)d_ws;
    auto alloc = [&](size_t bytes) { char* r = p; p += (bytes + 255) & ~(size_t)255; return r; };
    ushort* zsB   = (ushort*)alloc((size_t)MROWS * D_INNER * 2);
    ushort* xcB   = (ushort*)alloc((size_t)MROWS * D_INNER * 2);
    float*  dbl   = (float*)alloc((size_t)MROWS * 48 * 4);
    float*  Ssum  = (float*)alloc((size_t)NCH * 16 * D_INNER * 4);
    float*  sdsum = (float*)alloc((size_t)NCH * D_INNER * 4);
    ushort* ipwT  = (ushort*)alloc((size_t)DEPTH * 262144 * 2);
    ushort* xpwT  = (ushort*)alloc((size_t)DEPTH * 24576 * 2);
    ushort* opwT  = (ushort*)alloc((size_t)DEPTH * 131072 * 2);

    k_cvt<<<512, 256, 0, stream>>>(ipw, xpw, opw, ipwT, xpwT, opwT);

    for (int lyr = 0; lyr < DEPTH; lyr++) {
        const float* xin = (lyr == 0) ? x : out;
        float* xout = out;
        const float* alogL = alog + (size_t)lyr * D_INNER * D_STATE;
        const float* dpwL  = dpw + (size_t)lyr * D_INNER * DT_RANK;
        const float* dpbL  = dpb + lyr * D_INNER;

        k_front<<<NCH, 512, 0, stream>>>(
            xin, lnw + lyr * D_MODEL, lnb + lyr * D_MODEL,
            ipwT + (size_t)lyr * 262144,
            cw + (size_t)lyr * D_INNER * D_CONV, cb + lyr * D_INNER,
            xpwT + (size_t)lyr * 24576, dpwL, dpbL, alogL,
            zsB, xcB, dbl, Ssum, sdsum);

        k_comb<<<512, 512, 0, stream>>>(alogL, sdsum, Ssum);

        k_back<<<NCH / 2, 512, 0, stream>>>(
            dbl, xcB, zsB, Ssum, dpwL, dpbL, alogL,
            dpar + lyr * D_INNER,
            opwT + (size_t)lyr * 131072, xin, xout);
    }
}

// Round 13
// 200.271 us; speedup vs baseline: 1.0498x; 1.0058x over previous
//
#include <hip/hip_runtime.h>
#include <hip/hip_bf16.h>
#include <math.h>

// Problem constants
#define D_MODEL 256
#define DEPTH 2
#define D_INNER 512
#define D_STATE 16
#define D_CONV 4
#define DT_RANK 16
#define BATCH 2
#define SEQLEN 2048
#define MROWS (BATCH * SEQLEN)   // 4096

#define LCH 8     // rows per chunk (front)
#define NCH 512   // total chunks
#define CPB 256   // chunks per batch

typedef __attribute__((ext_vector_type(8))) short bf16x8;
typedef __attribute__((ext_vector_type(4))) float f32x4;

__device__ __forceinline__ float silu(float v) {
    return v / (1.0f + __expf(-v));
}

__device__ __forceinline__ ushort f2bf(float f) {
    union { float f; unsigned u; } v; v.f = f;
    unsigned r = v.u + 0x7FFFu + ((v.u >> 16) & 1u);
    return (ushort)(r >> 16);
}

__device__ __forceinline__ float bf2f(ushort u) {
    union { unsigned u; float f; } v; v.u = ((unsigned)u) << 16;
    return v.f;
}

__device__ __forceinline__ float softplus_f(float x) {
    return (x > 20.f) ? x : __logf(1.f + __expf(x));
}

#define HS_STR 264   // ushort stride, bf16 LN output (16 rows, 11 valid)
#define XC_STR 520   // ushort stride, xc/yy LDS tiles

// ---------------------------------------------------------------------------
// k_cvt: f32 -> bf16 AND re-layout to MFMA tile-major: per (nt,kt) a 1-KB
// tile [16 r][32 c] so one wave weight-load = one coalesced 1-KB segment.
// ---------------------------------------------------------------------------
__global__ __launch_bounds__(256) void k_cvt(
    const float* __restrict__ ipw, const float* __restrict__ xpw,
    const float* __restrict__ opw, ushort* __restrict__ ipwT,
    ushort* __restrict__ xpwT, ushort* __restrict__ opwT)
{
    size_t tid = (size_t)blockIdx.x * 256 + threadIdx.x;
    {   // ipw: [2][1024 n][256 k] -> per layer [64 nt][8 kt][16 r][32 c]
        int lyr = (int)(tid >> 16), rem = (int)(tid & 65535);
        int n = rem >> 6, k = (rem & 63) * 4;
        float4 v = *(const float4*)(ipw + ((size_t)lyr * 1024 + n) * 256 + k);
        int nt = n >> 4, r = n & 15, kt = k >> 5, c = k & 31;
        ushort4 o = { f2bf(v.x), f2bf(v.y), f2bf(v.z), f2bf(v.w) };
        *(ushort4*)(ipwT + (size_t)lyr * 262144 + (nt * 8 + kt) * 512 + r * 32 + c) = o;
    }
    if (tid < 12288) {   // xpw: [2][48][512] -> per layer [3 nt][16 kt] tiles
        int lyr = (int)(tid / 6144), rem = (int)(tid % 6144);
        int n = rem >> 7, k = (rem & 127) * 4;
        float4 v = *(const float4*)(xpw + ((size_t)lyr * 48 + n) * 512 + k);
        int nt = n >> 4, r = n & 15, kt = k >> 5, c = k & 31;
        ushort4 o = { f2bf(v.x), f2bf(v.y), f2bf(v.z), f2bf(v.w) };
        *(ushort4*)(xpwT + (size_t)lyr * 24576 + (nt * 16 + kt) * 512 + r * 32 + c) = o;
    }
    if (tid < 65536) {   // opw: [2][256][512] -> per layer [16 nt][16 kt]
        int lyr = (int)(tid >> 15), rem = (int)(tid & 32767);
        int n = rem >> 7, k = (rem & 127) * 4;
        float4 v = *(const float4*)(opw + ((size_t)lyr * 256 + n) * 512 + k);
        int nt = n >> 4, r = n & 15, kt = k >> 5, c = k & 31;
        ushort4 o = { f2bf(v.x), f2bf(v.y), f2bf(v.z), f2bf(v.w) };
        *(ushort4*)(opwT + (size_t)lyr * 131072 + (nt * 16 + kt) * 512 + r * 32 + c) = o;
    }
}

// ---------------------------------------------------------------------------
// k_front: 8-row chunk, 4 phases / 3 barriers, LDS 34.9 KB.
//   LN (direct global reads) | in_proj MFMA + in-register conv | x_proj MFMA
//   waves 0-2 ∥ coalesced xcB/zsB drain waves 3-7 | scan_sum.
// bounds(512,2): VGPR cap 256 so the 2-deep weight ping-pong and bw[16]
// prefetch stay in registers (at (512,4) the compiler squeezed to 60 VGPR
// for 8 waves/EU and elided the double-buffer — R12 evidence).
// Grid 512 x 512.
// ---------------------------------------------------------------------------
__global__ __launch_bounds__(512, 2) void k_front(
    const float* __restrict__ xin, const float* __restrict__ lnwL,
    const float* __restrict__ lnbL, const ushort* __restrict__ ipwT,
    const float* __restrict__ cwL, const float* __restrict__ cbL,
    const ushort* __restrict__ xpwT, const float* __restrict__ dpwL,
    const float* __restrict__ dpbL, const float* __restrict__ alogL,
    ushort* __restrict__ zsB, ushort* __restrict__ xcB,
    float* __restrict__ dbl, float* __restrict__ Ssum,
    float* __restrict__ sdsum)
{
    const int t = threadIdx.x, bid = blockIdx.x;
    const int lane = t & 63, w = t >> 6, l15 = lane & 15, quad = lane >> 4;
    __shared__ ushort hs[16 * HS_STR];                     //  8.4 KB
    __shared__ __align__(16) ushort xc_s[16 * XC_STR];     // 16.6 KB
    __shared__ __align__(16) ushort z_s[8 * 512];          //  8.2 KB
    __shared__ float  dbl_s[8 * 52];                       //  1.7 KB
    int m0 = bid * LCH;

    // ---- LayerNorm: 11 rows x 32 threads, direct global loads ----
    if (t < 11 * 32) {
        int r = t >> 5, ci = t & 31;
        int grow = m0 - 3 + r; if (grow < 0) grow = 0;
        const float* xr = xin + (size_t)grow * D_MODEL + ci * 8;
        float4 v0 = *(const float4*)xr;
        float4 v1 = *(const float4*)(xr + 4);
        float vals[8] = { v0.x, v0.y, v0.z, v0.w, v1.x, v1.y, v1.z, v1.w };
        float s = 0.f, sq = 0.f;
        #pragma unroll
        for (int k = 0; k < 8; k++) { s += vals[k]; sq += vals[k] * vals[k]; }
        #pragma unroll
        for (int off = 1; off < 32; off <<= 1) {
            s  += __shfl_xor(s, off, 32);
            sq += __shfl_xor(sq, off, 32);
        }
        float mu  = s * (1.0f / 256.f);
        float var = sq * (1.0f / 256.f) - mu * mu;
        float rst = rsqrtf(var + 1e-5f);
        #pragma unroll
        for (int k = 0; k < 8; k++) {
            int c = ci * 8 + k;
            hs[r * HS_STR + c] = f2bf((vals[k] - mu) * rst * lnwL[c] + lnbL[c]);
        }
    }
    __syncthreads();

    // ---- in_proj MFMA (f split 4+4, 2-deep weight dbuf) + fused conv ----
    {
        bf16x8 af[8];
        #pragma unroll
        for (int k8 = 0; k8 < 8; k8++)
            af[k8] = *(const bf16x8*)&hs[l15 * HS_STR + quad * 8 + k8 * 32];
        const ushort* wb = ipwT + (size_t)w * 64 * 512 + l15 * 32 + quad * 8;

        #pragma unroll
        for (int half = 0; half < 2; half++) {
            const ushort* wh = wb + (size_t)half * 4 * 8 * 512;
            f32x4 acc[4];
            #pragma unroll
            for (int f = 0; f < 4; f++) acc[f] = (f32x4){0.f, 0.f, 0.f, 0.f};
            bf16x8 bA[4], bB[4];
            #pragma unroll
            for (int f = 0; f < 4; f++) bA[f] = *(const bf16x8*)(wh + (f * 8) * 512);
            #pragma unroll
            for (int k8 = 0; k8 < 8; k8++) {
                bf16x8* cur = (k8 & 1) ? bB : bA;
                bf16x8* nxt = (k8 & 1) ? bA : bB;
                if (k8 < 7) {
                    #pragma unroll
                    for (int f = 0; f < 4; f++)
                        nxt[f] = *(const bf16x8*)(wh + (f * 8 + k8 + 1) * 512);
                }
                #pragma unroll
                for (int f = 0; f < 4; f++)
                    acc[f] = __builtin_amdgcn_mfma_f32_16x16x32_bf16(af[k8], cur[f], acc[f], 0, 0, 0);
            }

            if (w < 4) {
                // fused conv (R9-verified): xi rows live in acc across quads;
                // conv weights straight from L2 (16 consecutive float4/quad).
                #pragma unroll
                for (int f = 0; f < 4; f++) {
                    int n = w * 128 + (half * 4 + f) * 16 + l15;
                    float x0 = acc[f][0], x1 = acc[f][1], x2 = acc[f][2], x3 = acc[f][3];
                    float p1 = __shfl_up(x1, 16);
                    float p2 = __shfl_up(x2, 16);
                    float p3 = __shfl_up(x3, 16);
                    float4 cwv = *(const float4*)(cwL + n * 4);
                    float cbv = cbL[n];
                    int jb = quad * 4 - 3;
                    #define EMIT(JOFF, T0, T1, T2, T3)                          \
                    {   int j = jb + (JOFF);                                    \
                        if (j >= 0 && j < 8) {                                  \
                            int l = (m0 + j) & (SEQLEN - 1);                    \
                            float s = cbv;                                      \
                            if (l >= 3) s = fmaf(cwv.x, (T0), s);               \
                            if (l >= 2) s = fmaf(cwv.y, (T1), s);               \
                            if (l >= 1) s = fmaf(cwv.z, (T2), s);               \
                            s = fmaf(cwv.w, (T3), s);                           \
                            xc_s[j * XC_STR + n] = f2bf(silu(s));               \
                        }                                                       \
                    }
                    EMIT(0, p1, p2, p3, x0)
                    EMIT(1, p2, p3, x0, x1)
                    EMIT(2, p3, x0, x1, x2)
                    EMIT(3, x0, x1, x2, x3)
                    #undef EMIT
                }
            } else {
                // z path: n >= 512, valid rows rl 3..10 -> z_s rows 0..7 (LDS)
                #pragma unroll
                for (int f = 0; f < 4; f++) {
                    int n = w * 128 + (half * 4 + f) * 16 + l15;
                    #pragma unroll
                    for (int r2 = 0; r2 < 4; r2++) {
                        int rl = quad * 4 + r2;
                        if (rl >= 3 && rl < 11)
                            z_s[(rl - 3) * 512 + (n - 512)] = f2bf(silu(acc[f][r2]));
                    }
                }
            }
        }
    }

    // ---- hoist scan params + compute a[] (overlaps x_proj phase) ----
    float a[16], wdp[16];
    {
        float al[16];
        *(float4*)&al[0]   = *(const float4*)(alogL + (size_t)t * 16 + 0);
        *(float4*)&al[4]   = *(const float4*)(alogL + (size_t)t * 16 + 4);
        *(float4*)&al[8]   = *(const float4*)(alogL + (size_t)t * 16 + 8);
        *(float4*)&al[12]  = *(const float4*)(alogL + (size_t)t * 16 + 12);
        #pragma unroll
        for (int n = 0; n < 16; n++) a[n] = -__expf(al[n]);
    }
    *(float4*)&wdp[0]  = *(const float4*)(dpwL + (size_t)t * 16 + 0);
    *(float4*)&wdp[4]  = *(const float4*)(dpwL + (size_t)t * 16 + 4);
    *(float4*)&wdp[8]  = *(const float4*)(dpwL + (size_t)t * 16 + 8);
    *(float4*)&wdp[12] = *(const float4*)(dpwL + (size_t)t * 16 + 12);
    float bias = dpbL[t];
    __syncthreads();

    // ---- x_proj MFMA (waves 0-2) ∥ coalesced xcB/zsB drain (waves 3-7) ----
    if (w < 3) {
        const ushort* wb = xpwT + (size_t)w * 16 * 512 + l15 * 32 + quad * 8;
        bf16x8 bw[16];
        #pragma unroll
        for (int k8 = 0; k8 < 16; k8++)
            bw[k8] = *(const bf16x8*)(wb + k8 * 512);
        f32x4 acc = (f32x4){0.f, 0.f, 0.f, 0.f};
        #pragma unroll
        for (int k8 = 0; k8 < 16; k8++) {
            bf16x8 af = *(const bf16x8*)&xc_s[l15 * XC_STR + quad * 8 + k8 * 32];
            acc = __builtin_amdgcn_mfma_f32_16x16x32_bf16(af, bw[k8], acc, 0, 0, 0);
        }
        int n = w * 16 + l15;
        #pragma unroll
        for (int r2 = 0; r2 < 4; r2++) {
            int rl = quad * 4 + r2;
            if (rl < LCH) {
                dbl_s[rl * 52 + n] = acc[r2];
                dbl[(size_t)(m0 + rl) * 48 + n] = acc[r2];
            }
        }
    } else {
        // 320 idle threads stream 2 x 8 rows x 512 ushorts as ushort4.
        int ti = t - 192;
        for (int i = ti; i < 2048; i += 320) {
            int arr = i >> 10, rem = i & 1023;
            int row = rem >> 7, c4 = (rem & 127) * 4;
            if (arr == 0) {
                ushort4 v = *(const ushort4*)&xc_s[row * XC_STR + c4];
                *(ushort4*)(xcB + (size_t)(m0 + row) * D_INNER + c4) = v;
            } else {
                ushort4 v = *(const ushort4*)&z_s[row * 512 + c4];
                *(ushort4*)(zsB + (size_t)(m0 + row) * D_INNER + c4) = v;
            }
        }
    }
    __syncthreads();

    // ---- scan_sum (d = t, all 512 threads), 8 serial steps ----
    {
        float h[16];
        #pragma unroll
        for (int n = 0; n < 16; n++) h[n] = 0.f;
        float sd = 0.f;
        for (int j = 0; j < LCH; j++) {
            const float* dp = &dbl_s[j * 52];
            float d0 = 0.f, d1 = 0.f;
            #pragma unroll
            for (int r2 = 0; r2 < 8; r2++) {
                d0 = fmaf(dp[r2], wdp[r2], d0);
                d1 = fmaf(dp[8 + r2], wdp[8 + r2], d1);
            }
            float dl = softplus_f(bias + d0 + d1);
            float xv = bf2f(xc_s[j * XC_STR + t]);
            float u = dl * xv;
            sd += dl;
            #pragma unroll
            for (int n = 0; n < 16; n++)
                h[n] = fmaf(__expf(dl * a[n]), h[n], dp[16 + n] * u);
        }
        size_t sbase = (size_t)bid * 16 * D_INNER + t;
        #pragma unroll
        for (int n = 0; n < 16; n++) Ssum[sbase + (size_t)n * D_INNER] = h[n];
        sdsum[(size_t)bid * D_INNER + t] = sd;
    }
}

// ---------------------------------------------------------------------------
// k_comb: two-level exclusive prefix over 512 chunk summaries. Grid 512x512.
// Only EVEN chunks' prefixes are stored (k_back consumes chunk 2*bid only).
// ---------------------------------------------------------------------------
__global__ __launch_bounds__(512, 4) void k_comb(
    const float* __restrict__ alogL, const float* __restrict__ sdsum,
    float* __restrict__ Ssum)
{
    const int t = threadIdx.x, bid = blockIdx.x;
    __shared__ float S_l[32][17], sd_l[32][17];
    int ch32 = t & 31, seg = t >> 5;
    int chain = bid * 32 + ch32;
    int d = chain & 511;
    int n = (chain >> 9) & 15;
    int b = chain >> 13;
    float a = -__expf(alogL[(size_t)d * 16 + n]);
    int c0 = b * CPB + seg * 16;

    float s_r[16], sd_r[16];
    float S = 0.f, sdt = 0.f;
    #pragma unroll
    for (int j = 0; j < 16; j++) {
        size_t c = (size_t)(c0 + j);
        float s  = Ssum[(c * 16 + n) * D_INNER + d];
        float sd = sdsum[c * D_INNER + d];
        s_r[j] = s; sd_r[j] = sd;
        S = fmaf(__expf(a * sd), S, s);
        sdt += sd;
    }
    S_l[ch32][seg] = S;
    sd_l[ch32][seg] = sdt;
    __syncthreads();

    if (t < 32) {
        float hi = 0.f;
        #pragma unroll
        for (int g = 0; g < 16; g++) {
            float Sv = S_l[t][g], sdv = sd_l[t][g];
            S_l[t][g] = hi;
            hi = fmaf(__expf(a * sdv), hi, Sv);
        }
    }
    __syncthreads();

    float hi = S_l[ch32][seg];
    #pragma unroll
    for (int j = 0; j < 16; j++) {
        size_t c = (size_t)(c0 + j);
        if (!(j & 1))   // c0 even, so c even iff j even
            Ssum[(c * 16 + n) * D_INNER + d] = hi;
        hi = fmaf(__expf(a * sd_r[j]), hi, s_r[j]);
    }
}

// ---------------------------------------------------------------------------
// k_back: TWO chunks (16 rows) per block. Grid 256 x 512.
// Rescan continues through both chunks; only even chunk's Ssum read.
// All loads hoisted/batched; out_proj full-density 16-row tiles.
// ---------------------------------------------------------------------------
__global__ __launch_bounds__(512, 2) void k_back(
    const float* __restrict__ dbl, const ushort* __restrict__ xcB,
    const ushort* __restrict__ zsB, const float* __restrict__ Ssum,
    const float* __restrict__ dpwL, const float* __restrict__ dpbL,
    const float* __restrict__ alogL, const float* __restrict__ dparL,
    const ushort* __restrict__ opwT, const float* __restrict__ xin,
    float* __restrict__ xout)
{
    const int t = threadIdx.x, bid = blockIdx.x;
    const int lane = t & 63, w = t >> 6, l15 = lane & 15, quad = lane >> 4;
    __shared__ ushort yy_s[16 * XC_STR];   // 16.6 KB, all 16 rows valid
    __shared__ float  dbl_l[16 * 48];      //  3.0 KB
    int m0 = bid * 16;

    // ---- stage both chunks' dbl rows into LDS ----
    for (int i = t; i < 16 * 48; i += 512) dbl_l[i] = dbl[(size_t)m0 * 48 + i];

    // ---- hoist ALL global inputs for the rescan (batched issue) ----
    ushort xcv[16], zsv[16];
    #pragma unroll
    for (int j = 0; j < 16; j++) {
        size_t rb = (size_t)(m0 + j) * D_INNER + t;
        xcv[j] = xcB[rb];
        zsv[j] = zsB[rb];
    }
    float h[16];
    {
        size_t sbase = ((size_t)(2 * bid) * 16) * D_INNER + t;  // even chunk
        #pragma unroll
        for (int n = 0; n < 16; n++) h[n] = Ssum[sbase + (size_t)n * D_INNER];
    }
    float a[16], wdp[16];
    {
        float al[16];
        *(float4*)&al[0]  = *(const float4*)(alogL + (size_t)t * 16 + 0);
        *(float4*)&al[4]  = *(const float4*)(alogL + (size_t)t * 16 + 4);
        *(float4*)&al[8]  = *(const float4*)(alogL + (size_t)t * 16 + 8);
        *(float4*)&al[12] = *(const float4*)(alogL + (size_t)t * 16 + 12);
        #pragma unroll
        for (int n = 0; n < 16; n++) a[n] = -__expf(al[n]);
    }
    *(float4*)&wdp[0]  = *(const float4*)(dpwL + (size_t)t * 16 + 0);
    *(float4*)&wdp[4]  = *(const float4*)(dpwL + (size_t)t * 16 + 4);
    *(float4*)&wdp[8]  = *(const float4*)(dpwL + (size_t)t * 16 + 8);
    *(float4*)&wdp[12] = *(const float4*)(dpwL + (size_t)t * 16 + 12);
    float bias = dpbL[t];
    float Dd = dparL[t];
    __syncthreads();

    // ---- rescan 16 rows, d = t ----
    for (int j = 0; j < 16; j++) {
        const float* dp = &dbl_l[j * 48];
        float d0 = 0.f, d1 = 0.f;
        #pragma unroll
        for (int r2 = 0; r2 < 8; r2++) {
            d0 = fmaf(dp[r2], wdp[r2], d0);
            d1 = fmaf(dp[8 + r2], wdp[8 + r2], d1);
        }
        float dl = softplus_f(bias + d0 + d1);
        float xv = bf2f(xcv[j]);
        float gate = bf2f(zsv[j]);
        float u = dl * xv;
        float y0 = 0.f, y1 = 0.f, y2 = 0.f, y3 = 0.f;
        #pragma unroll
        for (int q = 0; q < 4; q++) {
            h[4 * q + 0] = fmaf(__expf(dl * a[4 * q + 0]), h[4 * q + 0], dp[16 + 4 * q + 0] * u);
            h[4 * q + 1] = fmaf(__expf(dl * a[4 * q + 1]), h[4 * q + 1], dp[16 + 4 * q + 1] * u);
            h[4 * q + 2] = fmaf(__expf(dl * a[4 * q + 2]), h[4 * q + 2], dp[16 + 4 * q + 2] * u);
            h[4 * q + 3] = fmaf(__expf(dl * a[4 * q + 3]), h[4 * q + 3], dp[16 + 4 * q + 3] * u);
            y0 = fmaf(h[4 * q + 0], dp[32 + 4 * q + 0], y0);
            y1 = fmaf(h[4 * q + 1], dp[32 + 4 * q + 1], y1);
            y2 = fmaf(h[4 * q + 2], dp[32 + 4 * q + 2], y2);
            y3 = fmaf(h[4 * q + 3], dp[32 + 4 * q + 3], y3);
        }
        float y = (y0 + y1) + (y2 + y3) + xv * Dd;
        yy_s[j * XC_STR + t] = f2bf(y * gate);
    }
    __syncthreads();

    // ---- out_proj MFMA + residual: full 16-row tiles, 2-deep ping-pong ----
    {
        const ushort* wb = opwT + (size_t)w * 2 * 16 * 512 + l15 * 32 + quad * 8;
        f32x4 acc0 = (f32x4){0.f, 0.f, 0.f, 0.f};
        f32x4 acc1 = (f32x4){0.f, 0.f, 0.f, 0.f};
        bf16x8 bA0 = *(const bf16x8*)(wb + 0 * 512);
        bf16x8 bA1 = *(const bf16x8*)(wb + 16 * 512);
        bf16x8 bB0, bB1;
        #pragma unroll
        for (int k8 = 0; k8 < 16; k8++) {
            if (k8 < 15) {
                if (k8 & 1) { bA0 = *(const bf16x8*)(wb + (k8 + 1) * 512);
                              bA1 = *(const bf16x8*)(wb + (16 + k8 + 1) * 512); }
                else        { bB0 = *(const bf16x8*)(wb + (k8 + 1) * 512);
                              bB1 = *(const bf16x8*)(wb + (16 + k8 + 1) * 512); }
            }
            bf16x8 af = *(const bf16x8*)&yy_s[l15 * XC_STR + quad * 8 + k8 * 32];
            bf16x8 c0 = (k8 & 1) ? bB0 : bA0;
            bf16x8 c1 = (k8 & 1) ? bB1 : bA1;
            acc0 = __builtin_amdgcn_mfma_f32_16x16x32_bf16(af, c0, acc0, 0, 0, 0);
            acc1 = __builtin_amdgcn_mfma_f32_16x16x32_bf16(af, c1, acc1, 0, 0, 0);
        }
        #pragma unroll
        for (int f = 0; f < 2; f++) {
            int n = w * 32 + f * 16 + l15;
            const f32x4& acc = (f == 0) ? acc0 : acc1;
            #pragma unroll
            for (int r2 = 0; r2 < 4; r2++) {
                int row = m0 + quad * 4 + r2;
                xout[(size_t)row * D_MODEL + n] =
                    acc[r2] + xin[(size_t)row * D_MODEL + n];
            }
        }
    }
}

// ---------------------------------------------------------------------------
// Launch. Inter-layer activation routed through d_out.
// ---------------------------------------------------------------------------
extern "C" void kernel_launch(void* const* d_in, const int* in_sizes, int n_in,
                              void* d_out, int out_size, void* d_ws, size_t ws_size,
                              hipStream_t stream)
{
    const float* x    = (const float*)d_in[0];
    const float* lnw  = (const float*)d_in[1];
    const float* lnb  = (const float*)d_in[2];
    const float* ipw  = (const float*)d_in[3];
    const float* cw   = (const float*)d_in[4];
    const float* cb   = (const float*)d_in[5];
    const float* xpw  = (const float*)d_in[6];
    const float* dpw  = (const float*)d_in[7];
    const float* dpb  = (const float*)d_in[8];
    const float* alog = (const float*)d_in[9];
    const float* dpar = (const float*)d_in[10];
    const float* opw  = (const float*)d_in[11];
    float* out = (float*)d_out;

    char* p = (char*)d_ws;
    auto alloc = [&](size_t bytes) { char* r = p; p += (bytes + 255) & ~(size_t)255; return r; };
    ushort* zsB   = (ushort*)alloc((size_t)MROWS * D_INNER * 2);
    ushort* xcB   = (ushort*)alloc((size_t)MROWS * D_INNER * 2);
    float*  dbl   = (float*)alloc((size_t)MROWS * 48 * 4);
    float*  Ssum  = (float*)alloc((size_t)NCH * 16 * D_INNER * 4);
    float*  sdsum = (float*)alloc((size_t)NCH * D_INNER * 4);
    ushort* ipwT  = (ushort*)alloc((size_t)DEPTH * 262144 * 2);
    ushort* xpwT  = (ushort*)alloc((size_t)DEPTH * 24576 * 2);
    ushort* opwT  = (ushort*)alloc((size_t)DEPTH * 131072 * 2);

    k_cvt<<<512, 256, 0, stream>>>(ipw, xpw, opw, ipwT, xpwT, opwT);

    for (int lyr = 0; lyr < DEPTH; lyr++) {
        const float* xin = (lyr == 0) ? x : out;
        float* xout = out;
        const float* alogL = alog + (size_t)lyr * D_INNER * D_STATE;
        const float* dpwL  = dpw + (size_t)lyr * D_INNER * DT_RANK;
        const float* dpbL  = dpb + lyr * D_INNER;

        k_front<<<NCH, 512, 0, stream>>>(
            xin, lnw + lyr * D_MODEL, lnb + lyr * D_MODEL,
            ipwT + (size_t)lyr * 262144,
            cw + (size_t)lyr * D_INNER * D_CONV, cb + lyr * D_INNER,
            xpwT + (size_t)lyr * 24576, dpwL, dpbL, alogL,
            zsB, xcB, dbl, Ssum, sdsum);

        k_comb<<<512, 512, 0, stream>>>(alogL, sdsum, Ssum);

        k_back<<<NCH / 2, 512, 0, stream>>>(
            dbl, xcB, zsB, Ssum, dpwL, dpbL, alogL,
            dpar + lyr * D_INNER,
            opwT + (size_t)lyr * 131072, xin, xout);
    }
}